// Round 10
// baseline (1982.769 us; speedup 1.0000x reference)
//
#include <hip/hip_runtime.h>
#include <math.h>

#define Bq 4
#define Tq 2048
#define Cq 1024
#define Hq 16
#define Nq 64

typedef __attribute__((ext_vector_type(8))) short short8v;
typedef __attribute__((ext_vector_type(4))) float f32x4;

__device__ inline float waveSum(float v) {
#pragma unroll
  for (int o = 32; o; o >>= 1) v += __shfl_xor(v, o);
  return v;
}
__device__ inline unsigned short f2bf(float f) {
  unsigned u = __float_as_uint(f);
  unsigned r = (u + 0x7FFFu + ((u >> 16) & 1u)) >> 16;
  return (unsigned short)r;
}
__device__ inline float bf2f(unsigned short b) {
  return __uint_as_float(((unsigned)b) << 16);
}

__global__ __launch_bounds__(256) void f32_to_bf16_kernel(
    const float* __restrict__ src, unsigned short* __restrict__ dst, int n4)
{
  int i = blockIdx.x * 256 + threadIdx.x;
  if (i >= n4) return;
  float4 v = ((const float4*)src)[i];
  ushort4 o;
  o.x = f2bf(v.x); o.y = f2bf(v.y); o.z = f2bf(v.z); o.w = f2bf(v.w);
  ((ushort4*)dst)[i] = o;
}

__global__ __launch_bounds__(256) void f32_to_bf16_hilo_kernel(
    const float* __restrict__ src, unsigned short* __restrict__ hi,
    unsigned short* __restrict__ lo, int n4)
{
  int i = blockIdx.x * 256 + threadIdx.x;
  if (i >= n4) return;
  float4 v = ((const float4*)src)[i];
  ushort4 h, l;
  h.x = f2bf(v.x); l.x = f2bf(v.x - bf2f(h.x));
  h.y = f2bf(v.y); l.y = f2bf(v.y - bf2f(h.y));
  h.z = f2bf(v.z); l.z = f2bf(v.z - bf2f(h.z));
  h.w = f2bf(v.w); l.w = f2bf(v.w - bf2f(h.w));
  ((ushort4*)hi)[i] = h;
  ((ushort4*)lo)[i] = l;
}

// ---- bf16 MFMA GEMM (plain) ----
__global__ __launch_bounds__(256) void gemm_bf16(
    const unsigned short* __restrict__ A, const unsigned short* __restrict__ W,
    float* __restrict__ dst, const float* __restrict__ extra,
    const float* __restrict__ lamb_p, int mode)
{
  const int m0 = blockIdx.x * 128, n0 = blockIdx.y * 128;
  const int tid = threadIdx.x;
  const int w = tid >> 6, l = tid & 63;
  const int wr = w >> 1, wc = w & 1;
  const int lrow = l & 15;
  const int lk = (l >> 4) * 8;

  f32x4 acc[4][4];
#pragma unroll
  for (int i = 0; i < 4; ++i)
#pragma unroll
    for (int j = 0; j < 4; ++j) acc[i][j] = (f32x4){0.f, 0.f, 0.f, 0.f};

  const unsigned short* Ab = A + (((size_t)(m0 + wr * 64 + lrow)) << 10) + lk;
  const unsigned short* Wb = W + (((size_t)(n0 + wc * 64 + lrow)) << 10) + lk;

  for (int k0 = 0; k0 < 1024; k0 += 32) {
    short8v a[4], b[4];
#pragma unroll
    for (int i = 0; i < 4; ++i) a[i] = *(const short8v*)(Ab + (((size_t)i) << 14) + k0);
#pragma unroll
    for (int j = 0; j < 4; ++j) b[j] = *(const short8v*)(Wb + (((size_t)j) << 14) + k0);
#pragma unroll
    for (int i = 0; i < 4; ++i)
#pragma unroll
      for (int j = 0; j < 4; ++j)
        acc[i][j] = __builtin_amdgcn_mfma_f32_16x16x32_bf16(a[i], b[j], acc[i][j], 0, 0, 0);
  }

  const float lam = (mode == 2) ? lamb_p[0] : 0.0f;
#pragma unroll
  for (int i = 0; i < 4; ++i)
#pragma unroll
    for (int j = 0; j < 4; ++j)
#pragma unroll
      for (int rg = 0; rg < 4; ++rg) {
        int m = m0 + wr * 64 + i * 16 + (l >> 4) * 4 + rg;
        int n = n0 + wc * 64 + j * 16 + (l & 15);
        float v = acc[i][j][rg];
        if (mode == 3) {
          dst[(size_t)m * Cq + n] = v + extra[(size_t)m * Cq + n];
        } else {
          if (mode == 2) v = (1.0f - lam) * v + lam * extra[(size_t)m * Cq + n];
          int b = m >> 11, t = m & (Tq - 1);
          int h = n >> 6, nn = n & 63;
          dst[((((size_t)b * Hq + h) * Tq + t) << 6) | nn] = v;
        }
      }
}

// ---- split-precision bf16 MFMA GEMM (K path) ----
__global__ __launch_bounds__(256) void gemm_bf16_split(
    const unsigned short* __restrict__ Ah, const unsigned short* __restrict__ Al,
    const unsigned short* __restrict__ Wh, const unsigned short* __restrict__ Wl,
    float* __restrict__ dst)
{
  const int m0 = blockIdx.x * 128, n0 = blockIdx.y * 128;
  const int tid = threadIdx.x;
  const int w = tid >> 6, l = tid & 63;
  const int wr = w >> 1, wc = w & 1;
  const int lrow = l & 15;
  const int lk = (l >> 4) * 8;

  f32x4 acc[4][4];
#pragma unroll
  for (int i = 0; i < 4; ++i)
#pragma unroll
    for (int j = 0; j < 4; ++j) acc[i][j] = (f32x4){0.f, 0.f, 0.f, 0.f};

  const size_t aoff = (((size_t)(m0 + wr * 64 + lrow)) << 10) + lk;
  const size_t woff = (((size_t)(n0 + wc * 64 + lrow)) << 10) + lk;
  const unsigned short* Ahb = Ah + aoff;
  const unsigned short* Alb = Al + aoff;
  const unsigned short* Whb = Wh + woff;
  const unsigned short* Wlb = Wl + woff;

  for (int k0 = 0; k0 < 1024; k0 += 32) {
    short8v ah[4], al[4], bh[4], bl[4];
#pragma unroll
    for (int i = 0; i < 4; ++i) {
      ah[i] = *(const short8v*)(Ahb + (((size_t)i) << 14) + k0);
      al[i] = *(const short8v*)(Alb + (((size_t)i) << 14) + k0);
    }
#pragma unroll
    for (int j = 0; j < 4; ++j) {
      bh[j] = *(const short8v*)(Whb + (((size_t)j) << 14) + k0);
      bl[j] = *(const short8v*)(Wlb + (((size_t)j) << 14) + k0);
    }
#pragma unroll
    for (int i = 0; i < 4; ++i)
#pragma unroll
      for (int j = 0; j < 4; ++j) {
        acc[i][j] = __builtin_amdgcn_mfma_f32_16x16x32_bf16(ah[i], bh[j], acc[i][j], 0, 0, 0);
        acc[i][j] = __builtin_amdgcn_mfma_f32_16x16x32_bf16(ah[i], bl[j], acc[i][j], 0, 0, 0);
        acc[i][j] = __builtin_amdgcn_mfma_f32_16x16x32_bf16(al[i], bh[j], acc[i][j], 0, 0, 0);
      }
  }

#pragma unroll
  for (int i = 0; i < 4; ++i)
#pragma unroll
    for (int j = 0; j < 4; ++j)
#pragma unroll
      for (int rg = 0; rg < 4; ++rg) {
        int m = m0 + wr * 64 + i * 16 + (l >> 4) * 4 + rg;
        int n = n0 + wc * 64 + j * 16 + (l & 15);
        int b = m >> 11, t = m & (Tq - 1);
        int h = n >> 6, nn = n & 63;
        dst[((((size_t)b * Hq + h) * Tq + t) << 6) | nn] = acc[i][j][rg];
      }
}

// LN (optional) + token-shift + RoPE (optional). src in (B,H,T,N).
__global__ __launch_bounds__(256) void postproc(
    const float* __restrict__ src, float* __restrict__ dst,
    unsigned short* __restrict__ dst_bf,
    const float* __restrict__ lnw, const float* __restrict__ lnb,
    const float* __restrict__ xs_p, int doLNRope)
{
  const int w = threadIdx.x >> 6, lane = threadIdx.x & 63;
  const int row = blockIdx.x * 4 + w;
  const int t = row & (Tq - 1);
  const int h = (row >> 11) & (Hq - 1);
  const size_t base = (size_t)row << 6;
  const size_t pbase = (t > 0) ? base - 64 : base;
  float cur = src[base + lane];
  float prv = src[pbase + lane];
  if (doLNRope) {
    const float lw = lnw[lane], lb = lnb[lane];
    {
      float m = waveSum(cur) * (1.0f / 64.0f);
      float d = cur - m;
      float var = waveSum(d * d) * (1.0f / 64.0f);
      cur = d * rsqrtf(var + 1e-5f) * lw + lb;
    }
    {
      float m = waveSum(prv) * (1.0f / 64.0f);
      float d = prv - m;
      float var = waveSum(d * d) * (1.0f / 64.0f);
      prv = d * rsqrtf(var + 1e-5f) * lw + lb;
    }
  }
  const float xv = xs_p[h * 64 + lane];
  float val = cur + xv * (prv - cur);
  if (doLNRope) {
    float partner = __shfl_xor(val, 1);
    if (lane < 32) {
      int i = lane >> 1;
      float freq = (float)exp((double)i * (-log(10000.0) / 15.0));
      float th = (float)t * freq;
      float c = cosf(th), s = sinf(th);
      val = c * val + ((lane & 1) ? -s : s) * partner;
    }
  }
  if (dst) dst[base + lane] = val;
  if (dst_bf) dst_bf[base + lane] = f2bf(val);
}

__global__ __launch_bounds__(256) void kw_kernel(
    const float* __restrict__ x, const float* __restrict__ Wkw, float* __restrict__ out)
{
  const int bt = blockIdx.x;
  const int tid = threadIdx.x, w = tid >> 6, lane = tid & 63;
  __shared__ float xs[Cq];
  for (int i = tid; i < Cq; i += 256) xs[i] = x[(size_t)bt * Cq + i];
  __syncthreads();
  const int b = bt >> 11, t = bt & (Tq - 1);
  for (int h = w; h < Hq; h += 4) {
    float acc = 0.0f;
    for (int i = lane; i < Cq; i += 64) acc += xs[i] * Wkw[h * Cq + i];
    acc = waveSum(acc);
    if (lane == 0) out[((size_t)(b * Hq + h)) * Tq + t] = 1.0f / (1.0f + expf(-acc));
  }
}

// Phase A: state evolution, 64 blocks x 1024 threads. State in registers.
// sim = MFMA (hi/lo bf16 split, 3 terms) over full K=64; fused argmax with
// exact first-index tie-break; cnt-gated deterministic scatter.
__global__ __launch_bounds__(1024, 1) void state_evolve_kernel(
    const float* __restrict__ kf, const unsigned short* __restrict__ v_bf,
    const float* __restrict__ kwp,
    unsigned short* __restrict__ dkn_bf, unsigned short* __restrict__ vst_bf,
    float* __restrict__ cnt_snap,
    const float* __restrict__ lnw, const float* __restrict__ lnb)
{
  const int bh = blockIdx.x;
  const int tid = threadIdx.x;
  const int s = tid >> 2, qd = tid & 3;
  const int db = qd * 16;
  const size_t seq = (size_t)Tq * Nq;
  const float* kb_ = kf + (size_t)bh * seq;
  const unsigned short* vb_ = v_bf + (size_t)bh * seq;
  const float* kwb = kwp + (size_t)bh * Tq;

  __shared__ unsigned short ck0h[256 * 72];  // bf16 hi of ck0, stride-72 rows
  __shared__ unsigned short ck0l[256 * 72];  // bf16 lo
  __shared__ unsigned short dknh[256 * 72];
  __shared__ unsigned short dknl[256 * 72];
  __shared__ float lwS[64], lbS[64];
  __shared__ float kwS[256];
  __shared__ int best[256];
  __shared__ int cntS[256];
  __shared__ float candV[4][256];
  __shared__ int candI[4][256];

  if (tid < 64) { lwS[tid] = lnw[tid]; lbS[tid] = lnb[tid]; }

  float dkReg[16], dvReg[16];
#pragma unroll
  for (int i = 0; i < 16; ++i) { dkReg[i] = 0.f; dvReg[i] = 0.f; }
  float cnt = 0.f;
  __syncthreads();

  for (int c = 0; c < 8; ++c) {
    const int e = c * 256 + 256;
    const int bb = (e - 512 > 0) ? (e - 512) : 0;

    // ---- phase A: LN(d_k) -> snapshot (+ LDS hi/lo for sim); v_state; cnt
    {
      float sum = 0.f;
#pragma unroll
      for (int i = 0; i < 16; ++i) sum += dkReg[i];
      sum += __shfl_xor(sum, 1); sum += __shfl_xor(sum, 2);
      const float mean = sum * (1.0f / 64.0f);
      float sq = 0.f;
#pragma unroll
      for (int i = 0; i < 16; ++i) { float d = dkReg[i] - mean; sq += d * d; }
      sq += __shfl_xor(sq, 1); sq += __shfl_xor(sq, 2);
      const float rs = rsqrtf(sq * (1.0f / 64.0f) + 1e-5f);
      float kn[16];
#pragma unroll
      for (int i = 0; i < 16; ++i)
        kn[i] = (dkReg[i] - mean) * rs * lwS[db + i] + lbS[db + i];
      unsigned short h16[16], l16[16];
#pragma unroll
      for (int i = 0; i < 16; ++i) {
        h16[i] = f2bf(kn[i]);
        l16[i] = f2bf(kn[i] - bf2f(h16[i]));
      }
      unsigned pk[8];
#pragma unroll
      for (int i2 = 0; i2 < 8; ++i2)
        pk[i2] = (unsigned)h16[2 * i2] | ((unsigned)h16[2 * i2 + 1] << 16);
      unsigned short* kd = dkn_bf + (((size_t)bh * 8 + c) << 14) + s * 64 + db;
      *(uint4*)kd = make_uint4(pk[0], pk[1], pk[2], pk[3]);
      *(uint4*)(kd + 8) = make_uint4(pk[4], pk[5], pk[6], pk[7]);
      if (c >= 1 && c <= 6) {
        *(uint4*)&dknh[s * 72 + db] = make_uint4(pk[0], pk[1], pk[2], pk[3]);
        *(uint4*)&dknh[s * 72 + db + 8] = make_uint4(pk[4], pk[5], pk[6], pk[7]);
        unsigned pl[8];
#pragma unroll
        for (int i2 = 0; i2 < 8; ++i2)
          pl[i2] = (unsigned)l16[2 * i2] | ((unsigned)l16[2 * i2 + 1] << 16);
        *(uint4*)&dknl[s * 72 + db] = make_uint4(pl[0], pl[1], pl[2], pl[3]);
        *(uint4*)&dknl[s * 72 + db + 8] = make_uint4(pl[4], pl[5], pl[6], pl[7]);
      }

      float sqv = 0.f;
#pragma unroll
      for (int i = 0; i < 16; ++i) sqv += dvReg[i] * dvReg[i];
      sqv += __shfl_xor(sqv, 1); sqv += __shfl_xor(sqv, 2);
      const float inrm = 1.0f / fmaxf(sqrtf(sqv), 1e-12f);
      unsigned pv[8];
#pragma unroll
      for (int i2 = 0; i2 < 8; ++i2)
        pv[i2] = (unsigned)f2bf(dvReg[2 * i2] * inrm) |
                 ((unsigned)f2bf(dvReg[2 * i2 + 1] * inrm) << 16);
      unsigned short* vd = vst_bf + (((size_t)bh * 8 + c) << 14) + s * 64 + db;
      *(uint4*)vd = make_uint4(pv[0], pv[1], pv[2], pv[3]);
      *(uint4*)(vd + 8) = make_uint4(pv[4], pv[5], pv[6], pv[7]);
      if (qd == 0) cnt_snap[((size_t)bh * 8 + c) * 256 + s] = cnt;
    }

    if (c == 7) break;

    // ---- phase B: ck0 = LN(zero-first-32(k window)) -> hi/lo LDS; kw; presets
    {
      float kv[16];
      if (qd >= 2) {
        const float* krow = kb_ + (size_t)(bb + s) * 64 + db;
#pragma unroll
        for (int i = 0; i < 16; i += 4) {
          float4 t4 = *(const float4*)(krow + i);
          kv[i] = t4.x; kv[i + 1] = t4.y; kv[i + 2] = t4.z; kv[i + 3] = t4.w;
        }
      } else {
#pragma unroll
        for (int i = 0; i < 16; ++i) kv[i] = 0.f;
      }
      float sum = 0.f;
#pragma unroll
      for (int i = 0; i < 16; ++i) sum += kv[i];
      sum += __shfl_xor(sum, 1); sum += __shfl_xor(sum, 2);
      const float mean = sum * (1.0f / 64.0f);
      float sq = 0.f;
#pragma unroll
      for (int i = 0; i < 16; ++i) { float d = kv[i] - mean; sq += d * d; }
      sq += __shfl_xor(sq, 1); sq += __shfl_xor(sq, 2);
      const float rs = rsqrtf(sq * (1.0f / 64.0f) + 1e-5f);
      unsigned short h16[16], l16[16];
#pragma unroll
      for (int i = 0; i < 16; ++i) {
        float cv = (kv[i] - mean) * rs * lwS[db + i] + lbS[db + i];
        h16[i] = f2bf(cv);
        l16[i] = f2bf(cv - bf2f(h16[i]));
      }
      unsigned ph[8], pl[8];
#pragma unroll
      for (int i2 = 0; i2 < 8; ++i2) {
        ph[i2] = (unsigned)h16[2 * i2] | ((unsigned)h16[2 * i2 + 1] << 16);
        pl[i2] = (unsigned)l16[2 * i2] | ((unsigned)l16[2 * i2 + 1] << 16);
      }
      *(uint4*)&ck0h[s * 72 + db] = make_uint4(ph[0], ph[1], ph[2], ph[3]);
      *(uint4*)&ck0h[s * 72 + db + 8] = make_uint4(ph[4], ph[5], ph[6], ph[7]);
      *(uint4*)&ck0l[s * 72 + db] = make_uint4(pl[0], pl[1], pl[2], pl[3]);
      *(uint4*)&ck0l[s * 72 + db + 8] = make_uint4(pl[4], pl[5], pl[6], pl[7]);
      if (qd == 0) kwS[s] = kwb[bb + s];
      if (tid < 256) {
        if (c == 0) { best[tid] = 1; cntS[tid] = (tid == 1) ? 256 : 0; }
        else cntS[tid] = 0;
      }
    }
    __syncthreads();

    // ---- phase C: MFMA sim + fused argmax (chunks 1..6)
    if (c > 0) {
      const int w = tid >> 6, l = tid & 63;
      const int Rb = (w & 3) * 64, Sb = (w >> 2) * 64;
      const int lrow = l & 15, lko = (l >> 4) * 8;
#pragma unroll
      for (int p = 0; p < 4; ++p) {
        const int arow = (Rb + p * 16 + lrow) * 72 + lko;
        const short8v ah0 = *(const short8v*)&ck0h[arow];
        const short8v ah1 = *(const short8v*)&ck0h[arow + 32];
        const short8v al0 = *(const short8v*)&ck0l[arow];
        const short8v al1 = *(const short8v*)&ck0l[arow + 32];
        f32x4 sacc[4];
#pragma unroll
        for (int j = 0; j < 4; ++j) sacc[j] = (f32x4){0.f, 0.f, 0.f, 0.f};
#pragma unroll
        for (int j = 0; j < 4; ++j) {
          const int brow = (Sb + j * 16 + lrow) * 72 + lko;
          const short8v bh0 = *(const short8v*)&dknh[brow];
          const short8v bh1 = *(const short8v*)&dknh[brow + 32];
          const short8v bl0 = *(const short8v*)&dknl[brow];
          const short8v bl1 = *(const short8v*)&dknl[brow + 32];
          sacc[j] = __builtin_amdgcn_mfma_f32_16x16x32_bf16(ah0, bh0, sacc[j], 0, 0, 0);
          sacc[j] = __builtin_amdgcn_mfma_f32_16x16x32_bf16(ah1, bh1, sacc[j], 0, 0, 0);
          sacc[j] = __builtin_amdgcn_mfma_f32_16x16x32_bf16(ah0, bl0, sacc[j], 0, 0, 0);
          sacc[j] = __builtin_amdgcn_mfma_f32_16x16x32_bf16(ah1, bl1, sacc[j], 0, 0, 0);
          sacc[j] = __builtin_amdgcn_mfma_f32_16x16x32_bf16(al0, bh0, sacc[j], 0, 0, 0);
          sacc[j] = __builtin_amdgcn_mfma_f32_16x16x32_bf16(al1, bh1, sacc[j], 0, 0, 0);
        }
#pragma unroll
        for (int r = 0; r < 4; ++r) {
          float bv = -3.0e38f;
          int bi = 1 << 30;
#pragma unroll
          for (int j = 0; j < 4; ++j) {
            const int s2 = Sb + j * 16 + lrow;
            float v = sacc[j][r];
            if (s2 == 0) v = -1.0e30f;  // SINK
            if (v > bv || (v == bv && s2 < bi)) { bv = v; bi = s2; }
          }
#pragma unroll
          for (int o = 1; o <= 8; o <<= 1) {
            float ov = __shfl_xor(bv, o);
            int oi = __shfl_xor(bi, o);
            if (ov > bv || (ov == bv && oi < bi)) { bv = ov; bi = oi; }
          }
          if (lrow == 0) {
            const int rc = Rb + p * 16 + (l >> 4) * 4 + r;
            candV[w >> 2][rc] = bv;
            candI[w >> 2][rc] = bi;
          }
        }
      }
      __syncthreads();
      if (tid < 256) {
        float bv = candV[0][tid];
        int bi = candI[0][tid];
#pragma unroll
        for (int g = 1; g < 4; ++g) {
          float v = candV[g][tid];
          int i2 = candI[g][tid];
          if (v > bv || (v == bv && i2 < bi)) { bv = v; bi = i2; }
        }
        best[tid] = bi;
        atomicAdd(&cntS[bi], 1);
      }
      __syncthreads();
    }

    // ---- phase D: cnt-gated ownership scatter (ck0 from LDS hi+lo, V from L2)
    {
      const int need = cntS[s];
      if (need) {
        int found = 0;
        for (int rc = 0; rc < 256 && found < need; ++rc) {
          if (best[rc] == s) {
            const float kwv = kwS[rc];
            const int cb = rc * 72 + db;
            const uint4 h0 = *(const uint4*)&ck0h[cb];
            const uint4 h1 = *(const uint4*)&ck0h[cb + 8];
            const uint4 l0 = *(const uint4*)&ck0l[cb];
            const uint4 l1 = *(const uint4*)&ck0l[cb + 8];
            const unsigned hh[8] = {h0.x, h0.y, h0.z, h0.w, h1.x, h1.y, h1.z, h1.w};
            const unsigned ll[8] = {l0.x, l0.y, l0.z, l0.w, l1.x, l1.y, l1.z, l1.w};
#pragma unroll
            for (int i2 = 0; i2 < 8; ++i2) {
              float c0 = __uint_as_float((hh[i2] & 0xFFFFu) << 16) +
                         __uint_as_float((ll[i2] & 0xFFFFu) << 16);
              float c1 = __uint_as_float(hh[i2] & 0xFFFF0000u) +
                         __uint_as_float(ll[i2] & 0xFFFF0000u);
              dkReg[2 * i2] += c0 * kwv;
              dkReg[2 * i2 + 1] += c1 * kwv;
            }
            const unsigned short* vr = vb_ + (size_t)(bb + rc) * 64 + db;
            const uint4 v0 = *(const uint4*)vr;
            const uint4 v1 = *(const uint4*)(vr + 8);
            const unsigned vv[8] = {v0.x, v0.y, v0.z, v0.w, v1.x, v1.y, v1.z, v1.w};
#pragma unroll
            for (int i2 = 0; i2 < 8; ++i2) {
              dvReg[2 * i2] += __uint_as_float((vv[i2] & 0xFFFFu) << 16) * kwv;
              dvReg[2 * i2 + 1] += __uint_as_float(vv[i2] & 0xFFFF0000u) * kwv;
            }
            ++found;
          }
        }
        cnt += (float)need;
      }
    }
    __syncthreads();
  }
}

// Phase B: MFMA flash attention. Grid 1024 = (bh, c, half); 256 thr, 4 waves x 32 rows.
__global__ __launch_bounds__(256, 2) void attn_mfma_kernel(
    const unsigned short* __restrict__ q_bf, const unsigned short* __restrict__ k_bf,
    const unsigned short* __restrict__ v_bf,
    const unsigned short* __restrict__ dkn_bf, const unsigned short* __restrict__ vst_bf,
    const float* __restrict__ cnt_snap, float* __restrict__ y,
    const float* __restrict__ ftp, const float* __restrict__ stp)
{
  const int blk = blockIdx.x;
  const int bh = blk >> 4;
  const int c = (blk >> 1) & 7;
  const int half = blk & 1;
  const int h = bh & (Hq - 1);
  const int tid = threadIdx.x;
  const int w = tid >> 6, l = tid & 63;
  const int g = l >> 4, n = l & 15;
  const int rows0 = c * 256 + half * 128 + w * 32;
  const int e = c * 256 + 256;
  const int bb = (e - 512 > 0) ? (e - 512) : 0;
  const int nwt = (e - bb) >> 6;  // 4 or 8
  const float stsc = stp[h] * 0.125f, ftsc = ftp[h] * 0.125f;
  const size_t seq = (size_t)Tq * Nq;

  __shared__ unsigned short Ks[64 * 72];
  __shared__ unsigned short VTs[64 * 72];
  __shared__ unsigned short Ps[4][32 * 72];
  __shared__ float wts[64];

  short8v qf[2][2];
#pragma unroll
  for (int mt = 0; mt < 2; ++mt)
#pragma unroll
    for (int kh = 0; kh < 2; ++kh)
      qf[mt][kh] = *(const short8v*)(q_bf + (size_t)bh * seq +
                                     (size_t)(rows0 + mt * 16 + n) * 64 + kh * 32 + g * 8);

  f32x4 oacc[2][4];
#pragma unroll
  for (int mt = 0; mt < 2; ++mt)
#pragma unroll
    for (int dt = 0; dt < 4; ++dt) oacc[mt][dt] = (f32x4){0.f, 0.f, 0.f, 0.f};
  float rowM[2][4], rowL[2][4];
#pragma unroll
  for (int mt = 0; mt < 2; ++mt)
#pragma unroll
    for (int r = 0; r < 4; ++r) { rowM[mt][r] = -1.0e30f; rowL[mt][r] = 0.f; }

  const int nkt = 4 + nwt;
  for (int kt = 0; kt < nkt; ++kt) {
    const bool isState = kt < 4;
    const int t0 = isState ? kt * 64 : bb + (kt - 4) * 64;
    const unsigned short* ksrc = isState
        ? dkn_bf + (((size_t)bh * 8 + c) << 14) + (size_t)t0 * 64
        : k_bf + (size_t)bh * seq + (size_t)t0 * 64;
    const unsigned short* vsrc = isState
        ? vst_bf + (((size_t)bh * 8 + c) << 14) + (size_t)t0 * 64
        : v_bf + (size_t)bh * seq + (size_t)t0 * 64;

    __syncthreads();
    {
      const int row = tid >> 2, q4 = tid & 3;
      const unsigned short* src = ksrc + row * 64 + q4 * 16;
      *(uint4*)&Ks[row * 72 + q4 * 16] = *(const uint4*)src;
      *(uint4*)&Ks[row * 72 + q4 * 16 + 8] = *(const uint4*)(src + 8);
      const unsigned short* vs = vsrc + row * 64 + q4 * 16;
#pragma unroll
      for (int i = 0; i < 16; ++i) VTs[(q4 * 16 + i) * 72 + row] = vs[i];
      if (tid < 64)
        wts[tid] = isState ? cnt_snap[((size_t)bh * 8 + c) * 256 + kt * 64 + tid] : 1.0f;
    }
    __syncthreads();

    f32x4 sacc[2][4];
#pragma unroll
    for (int mt = 0; mt < 2; ++mt)
#pragma unroll
      for (int nt = 0; nt < 4; ++nt) sacc[mt][nt] = (f32x4){0.f, 0.f, 0.f, 0.f};
#pragma unroll
    for (int nt = 0; nt < 4; ++nt) {
      short8v kf0 = *(const short8v*)&Ks[(nt * 16 + n) * 72 + g * 8];
      short8v kf1 = *(const short8v*)&Ks[(nt * 16 + n) * 72 + 32 + g * 8];
#pragma unroll
      for (int mt = 0; mt < 2; ++mt) {
        sacc[mt][nt] = __builtin_amdgcn_mfma_f32_16x16x32_bf16(qf[mt][0], kf0, sacc[mt][nt], 0, 0, 0);
        sacc[mt][nt] = __builtin_amdgcn_mfma_f32_16x16x32_bf16(qf[mt][1], kf1, sacc[mt][nt], 0, 0, 0);
      }
    }

    const float scale = isState ? stsc : ftsc;
    float wt_n[4];
#pragma unroll
    for (int nt = 0; nt < 4; ++nt) wt_n[nt] = wts[nt * 16 + n];

#pragma unroll
    for (int mt = 0; mt < 2; ++mt) {
#pragma unroll
      for (int r = 0; r < 4; ++r) {
        float sv[4];
#pragma unroll
        for (int nt = 0; nt < 4; ++nt) {
          float s = sacc[mt][nt][r] * scale;
          if (!isState) {
            int qi = rows0 + mt * 16 + g * 4 + r;
            int kj = t0 + nt * 16 + n;
            if (kj > qi) s = -1.0e30f;
          }
          sv[nt] = s;
        }
        float tmax = fmaxf(fmaxf(sv[0], sv[1]), fmaxf(sv[2], sv[3]));
        tmax = fmaxf(tmax, __shfl_xor(tmax, 1));
        tmax = fmaxf(tmax, __shfl_xor(tmax, 2));
        tmax = fmaxf(tmax, __shfl_xor(tmax, 4));
        tmax = fmaxf(tmax, __shfl_xor(tmax, 8));
        const float Mold = rowM[mt][r];
        const float Mnew = fmaxf(Mold, tmax);
        const float al = __expf(Mold - Mnew);
        rowM[mt][r] = Mnew;
        float p[4], ts = 0.f;
#pragma unroll
        for (int nt = 0; nt < 4; ++nt) { p[nt] = __expf(sv[nt] - Mnew); ts += p[nt]; }
        ts += __shfl_xor(ts, 1);
        ts += __shfl_xor(ts, 2);
        ts += __shfl_xor(ts, 4);
        ts += __shfl_xor(ts, 8);
        rowL[mt][r] = rowL[mt][r] * al + ts;
#pragma unroll
        for (int dt = 0; dt < 4; ++dt) oacc[mt][dt][r] *= al;
        const int prow = (mt * 16 + g * 4 + r) * 72;
#pragma unroll
        for (int nt = 0; nt < 4; ++nt)
          Ps[w][prow + nt * 16 + n] = f2bf(p[nt] * wt_n[nt]);
      }
    }

    short8v pf[2][2];
#pragma unroll
    for (int mt = 0; mt < 2; ++mt)
#pragma unroll
      for (int jh = 0; jh < 2; ++jh)
        pf[mt][jh] = *(const short8v*)&Ps[w][(mt * 16 + n) * 72 + jh * 32 + g * 8];
#pragma unroll
    for (int dt = 0; dt < 4; ++dt) {
      short8v vf0 = *(const short8v*)&VTs[(dt * 16 + n) * 72 + g * 8];
      short8v vf1 = *(const short8v*)&VTs[(dt * 16 + n) * 72 + 32 + g * 8];
#pragma unroll
      for (int mt = 0; mt < 2; ++mt) {
        oacc[mt][dt] = __builtin_amdgcn_mfma_f32_16x16x32_bf16(pf[mt][0], vf0, oacc[mt][dt], 0, 0, 0);
        oacc[mt][dt] = __builtin_amdgcn_mfma_f32_16x16x32_bf16(pf[mt][1], vf1, oacc[mt][dt], 0, 0, 0);
      }
    }
  }

#pragma unroll
  for (int mt = 0; mt < 2; ++mt) {
#pragma unroll
    for (int r = 0; r < 4; ++r) {
      const float inv = 1.0f / rowL[mt][r];
      const int row = rows0 + mt * 16 + g * 4 + r;
#pragma unroll
      for (int dt = 0; dt < 4; ++dt)
        y[(size_t)bh * seq + (size_t)row * 64 + dt * 16 + n] = oacc[mt][dt][r] * inv;
    }
  }
}

// LN over C=1024 per (b,t); gathers from (B,H,T,N), writes bf16 (B,T,C)
__global__ __launch_bounds__(256) void final_ln(
    const float* __restrict__ y, const float* __restrict__ lnw,
    const float* __restrict__ lnb, unsigned short* __restrict__ dst)
{
  const int bt = blockIdx.x;
  const int b = bt >> 11, t = bt & (Tq - 1);
  const int tid = threadIdx.x, w = tid >> 6, lane = tid & 63;
  __shared__ float red[8];
  float v[4];
  float s = 0.0f;
#pragma unroll
  for (int i = 0; i < 4; ++i) {
    int c = tid + (i << 8);
    int h = c >> 6, n = c & 63;
    v[i] = y[((((size_t)b * Hq + h) * Tq + t) << 6) + n];
    s += v[i];
  }
  s = waveSum(s);
  if (lane == 0) red[w] = s;
  __syncthreads();
  const float mean = (red[0] + red[1] + red[2] + red[3]) * (1.0f / 1024.0f);
  float s2 = 0.0f;
#pragma unroll
  for (int i = 0; i < 4; ++i) { float d = v[i] - mean; s2 += d * d; }
  s2 = waveSum(s2);
  if (lane == 0) red[4 + w] = s2;
  __syncthreads();
  const float var = (red[4] + red[5] + red[6] + red[7]) * (1.0f / 1024.0f);
  const float rs = rsqrtf(var + 1e-5f);
#pragma unroll
  for (int i = 0; i < 4; ++i) {
    int c = tid + (i << 8);
    dst[(size_t)bt * Cq + c] = f2bf((v[i] - mean) * rs * lnw[c] + lnb[c]);
  }
}

extern "C" void kernel_launch(void* const* d_in, const int* in_sizes, int n_in,
                              void* d_out, int out_size, void* d_ws, size_t ws_size,
                              hipStream_t stream)
{
  (void)in_sizes; (void)n_in; (void)out_size; (void)ws_size;
  const float* residual = (const float*)d_in[0];
  const float* x        = (const float*)d_in[1];
  const float* v1       = (const float*)d_in[2];
  const float* Wq       = (const float*)d_in[6];
  const float* Wk       = (const float*)d_in[7];
  const float* Wv       = (const float*)d_in[8];
  const float* Wproj    = (const float*)d_in[9];
  const float* Wkw      = (const float*)d_in[10];
  const float* x_q      = (const float*)d_in[11];
  const float* x_k      = (const float*)d_in[12];
  const float* x_v      = (const float*)d_in[13];
  const float* lamb     = (const float*)d_in[14];
  const float* ln_q_w   = (const float*)d_in[15];
  const float* ln_q_b   = (const float*)d_in[16];
  const float* ln_k_w   = (const float*)d_in[17];
  const float* ln_k_b   = (const float*)d_in[18];
  const float* ln_dk_w  = (const float*)d_in[19];
  const float* ln_dk_b  = (const float*)d_in[20];
  const float* ln_res_w = (const float*)d_in[21];
  const float* ln_res_b = (const float*)d_in[22];
  const float* ftp      = (const float*)d_in[23];
  const float* stp      = (const float*)d_in[24];

  float* ws = (float*)d_ws;
  const size_t SZ = (size_t)Bq * Hq * Tq * Nq;  // 8388608
  float* q_raw = ws;
  float* ybuf  = ws;
  float* k_raw = ws + SZ;
  unsigned short* vst_bf = (unsigned short*)(ws + SZ);
  float* cnt_snap = ws + SZ + SZ / 2;
  float* v_mix = ws + 2 * SZ;
  unsigned short* ylnb_bf = (unsigned short*)(ws + 2 * SZ);
  float* k_fin = ws + 3 * SZ;
  unsigned short* q_bf = (unsigned short*)(ws + 4 * SZ);
  unsigned short* x_lo = q_bf;
  unsigned short* k_bf = q_bf + SZ;
  unsigned short* wk_hi = k_bf;
  unsigned short* wk_lo = wk_hi + (1u << 20);
  unsigned short* v_bf = (unsigned short*)(ws + 5 * SZ);
  unsigned short* xb   = v_bf + SZ;
  unsigned short* dkn_bf = xb;
  unsigned short* wqb = (unsigned short*)(ws + 6 * SZ);
  unsigned short* wvb = wqb + (1u << 20);
  unsigned short* wpb = wvb + (1u << 20);
  float* kwbuf = ws + 6 * SZ + ((3u << 20) >> 1);

  dim3 gb(256);
  dim3 ggb(64, 8);

  hipLaunchKernelGGL(f32_to_bf16_hilo_kernel, dim3((int)(SZ / 4 / 256)), gb, 0, stream,
                     x, xb, x_lo, (int)(SZ / 4));
  hipLaunchKernelGGL(f32_to_bf16_hilo_kernel, dim3(1024), gb, 0, stream,
                     Wk, wk_hi, wk_lo, 262144);
  hipLaunchKernelGGL(f32_to_bf16_kernel, dim3(1024), gb, 0, stream, Wq, wqb, 262144);
  hipLaunchKernelGGL(f32_to_bf16_kernel, dim3(1024), gb, 0, stream, Wv, wvb, 262144);
  hipLaunchKernelGGL(f32_to_bf16_kernel, dim3(1024), gb, 0, stream, Wproj, wpb, 262144);

  hipLaunchKernelGGL(gemm_bf16, ggb, gb, 0, stream, xb, wqb, q_raw, (const float*)nullptr, lamb, 1);
  hipLaunchKernelGGL(gemm_bf16_split, ggb, gb, 0, stream, xb, x_lo, wk_hi, wk_lo, k_raw);
  hipLaunchKernelGGL(gemm_bf16, ggb, gb, 0, stream, xb, wvb, v_mix, v1, lamb, 2);
  hipLaunchKernelGGL(kw_kernel, dim3(Bq * Tq), gb, 0, stream, x, Wkw, kwbuf);

  const int rows = Bq * Hq * Tq;
  hipLaunchKernelGGL(postproc, dim3(rows / 4), gb, 0, stream, q_raw, (float*)nullptr, q_bf, ln_q_w, ln_q_b, x_q, 1);
  hipLaunchKernelGGL(postproc, dim3(rows / 4), gb, 0, stream, k_raw, k_fin, k_bf, ln_k_w, ln_k_b, x_k, 1);
  hipLaunchKernelGGL(postproc, dim3(rows / 4), gb, 0, stream, v_mix, (float*)nullptr, v_bf,
                     (const float*)nullptr, (const float*)nullptr, x_v, 0);

  hipLaunchKernelGGL(state_evolve_kernel, dim3(Bq * Hq), dim3(1024), 0, stream,
                     k_fin, v_bf, kwbuf, dkn_bf, vst_bf, cnt_snap, ln_dk_w, ln_dk_b);

  hipLaunchKernelGGL(attn_mfma_kernel, dim3(Bq * Hq * 16), gb, 0, stream,
                     q_bf, k_bf, v_bf, dkn_bf, vst_bf, cnt_snap, ybuf, ftp, stp);

  hipLaunchKernelGGL(final_ln, dim3(Bq * Tq), gb, 0, stream, ybuf, ln_res_w, ln_res_b, ylnb_bf);
  hipLaunchKernelGGL(gemm_bf16, ggb, gb, 0, stream, ylnb_bf, wpb, (float*)d_out, residual, lamb, 3);
}

// Round 11
// 1510.106 us; speedup vs baseline: 1.3130x; 1.3130x over previous
//
#include <hip/hip_runtime.h>
#include <math.h>

#define Bq 4
#define Tq 2048
#define Cq 1024
#define Hq 16
#define Nq 64

typedef __attribute__((ext_vector_type(8))) short short8v;
typedef __attribute__((ext_vector_type(4))) float f32x4;

__device__ inline float waveSum(float v) {
#pragma unroll
  for (int o = 32; o; o >>= 1) v += __shfl_xor(v, o);
  return v;
}
__device__ inline unsigned short f2bf(float f) {
  unsigned u = __float_as_uint(f);
  unsigned r = (u + 0x7FFFu + ((u >> 16) & 1u)) >> 16;
  return (unsigned short)r;
}
__device__ inline float bf2f(unsigned short b) {
  return __uint_as_float(((unsigned)b) << 16);
}

__global__ __launch_bounds__(256) void f32_to_bf16_kernel(
    const float* __restrict__ src, unsigned short* __restrict__ dst, int n4)
{
  int i = blockIdx.x * 256 + threadIdx.x;
  if (i >= n4) return;
  float4 v = ((const float4*)src)[i];
  ushort4 o;
  o.x = f2bf(v.x); o.y = f2bf(v.y); o.z = f2bf(v.z); o.w = f2bf(v.w);
  ((ushort4*)dst)[i] = o;
}

__global__ __launch_bounds__(256) void f32_to_bf16_hilo_kernel(
    const float* __restrict__ src, unsigned short* __restrict__ hi,
    unsigned short* __restrict__ lo, int n4)
{
  int i = blockIdx.x * 256 + threadIdx.x;
  if (i >= n4) return;
  float4 v = ((const float4*)src)[i];
  ushort4 h, l;
  h.x = f2bf(v.x); l.x = f2bf(v.x - bf2f(h.x));
  h.y = f2bf(v.y); l.y = f2bf(v.y - bf2f(h.y));
  h.z = f2bf(v.z); l.z = f2bf(v.z - bf2f(h.z));
  h.w = f2bf(v.w); l.w = f2bf(v.w - bf2f(h.w));
  ((ushort4*)hi)[i] = h;
  ((ushort4*)lo)[i] = l;
}

// ---- bf16 MFMA GEMM (plain), register ping-pong pipelined ----
__global__ __launch_bounds__(256) void gemm_bf16(
    const unsigned short* __restrict__ A, const unsigned short* __restrict__ W,
    float* __restrict__ dst, const float* __restrict__ extra,
    const float* __restrict__ lamb_p, int mode)
{
  const int m0 = blockIdx.x * 128, n0 = blockIdx.y * 128;
  const int tid = threadIdx.x;
  const int w = tid >> 6, l = tid & 63;
  const int wr = w >> 1, wc = w & 1;
  const int lrow = l & 15;
  const int lk = (l >> 4) * 8;

  f32x4 acc[4][4];
#pragma unroll
  for (int i = 0; i < 4; ++i)
#pragma unroll
    for (int j = 0; j < 4; ++j) acc[i][j] = (f32x4){0.f, 0.f, 0.f, 0.f};

  const unsigned short* Ab = A + (((size_t)(m0 + wr * 64 + lrow)) << 10) + lk;
  const unsigned short* Wb = W + (((size_t)(n0 + wc * 64 + lrow)) << 10) + lk;

  short8v aA[4], bA[4], aB[4], bB[4];
#pragma unroll
  for (int i = 0; i < 4; ++i) aA[i] = *(const short8v*)(Ab + (((size_t)i) << 14));
#pragma unroll
  for (int j = 0; j < 4; ++j) bA[j] = *(const short8v*)(Wb + (((size_t)j) << 14));

#pragma unroll
  for (int k0 = 0; k0 < 1024; k0 += 64) {
#pragma unroll
    for (int i = 0; i < 4; ++i) aB[i] = *(const short8v*)(Ab + (((size_t)i) << 14) + k0 + 32);
#pragma unroll
    for (int j = 0; j < 4; ++j) bB[j] = *(const short8v*)(Wb + (((size_t)j) << 14) + k0 + 32);
#pragma unroll
    for (int i = 0; i < 4; ++i)
#pragma unroll
      for (int j = 0; j < 4; ++j)
        acc[i][j] = __builtin_amdgcn_mfma_f32_16x16x32_bf16(aA[i], bA[j], acc[i][j], 0, 0, 0);
    if (k0 + 64 < 1024) {
#pragma unroll
      for (int i = 0; i < 4; ++i) aA[i] = *(const short8v*)(Ab + (((size_t)i) << 14) + k0 + 64);
#pragma unroll
      for (int j = 0; j < 4; ++j) bA[j] = *(const short8v*)(Wb + (((size_t)j) << 14) + k0 + 64);
    }
#pragma unroll
    for (int i = 0; i < 4; ++i)
#pragma unroll
      for (int j = 0; j < 4; ++j)
        acc[i][j] = __builtin_amdgcn_mfma_f32_16x16x32_bf16(aB[i], bB[j], acc[i][j], 0, 0, 0);
  }

  const float lam = (mode == 2) ? lamb_p[0] : 0.0f;
#pragma unroll
  for (int i = 0; i < 4; ++i)
#pragma unroll
    for (int j = 0; j < 4; ++j)
#pragma unroll
      for (int rg = 0; rg < 4; ++rg) {
        int m = m0 + wr * 64 + i * 16 + (l >> 4) * 4 + rg;
        int n = n0 + wc * 64 + j * 16 + (l & 15);
        float v = acc[i][j][rg];
        if (mode == 3) {
          dst[(size_t)m * Cq + n] = v + extra[(size_t)m * Cq + n];
        } else {
          if (mode == 2) v = (1.0f - lam) * v + lam * extra[(size_t)m * Cq + n];
          int b = m >> 11, t = m & (Tq - 1);
          int h = n >> 6, nn = n & 63;
          dst[((((size_t)b * Hq + h) * Tq + t) << 6) | nn] = v;
        }
      }
}

// ---- split-precision bf16 MFMA GEMM (K path), ping-pong pipelined ----
__global__ __launch_bounds__(256) void gemm_bf16_split(
    const unsigned short* __restrict__ Ah, const unsigned short* __restrict__ Al,
    const unsigned short* __restrict__ Wh, const unsigned short* __restrict__ Wl,
    float* __restrict__ dst)
{
  const int m0 = blockIdx.x * 128, n0 = blockIdx.y * 128;
  const int tid = threadIdx.x;
  const int w = tid >> 6, l = tid & 63;
  const int wr = w >> 1, wc = w & 1;
  const int lrow = l & 15;
  const int lk = (l >> 4) * 8;

  f32x4 acc[4][4];
#pragma unroll
  for (int i = 0; i < 4; ++i)
#pragma unroll
    for (int j = 0; j < 4; ++j) acc[i][j] = (f32x4){0.f, 0.f, 0.f, 0.f};

  const size_t aoff = (((size_t)(m0 + wr * 64 + lrow)) << 10) + lk;
  const size_t woff = (((size_t)(n0 + wc * 64 + lrow)) << 10) + lk;
  const unsigned short* Ahb = Ah + aoff;
  const unsigned short* Alb = Al + aoff;
  const unsigned short* Whb = Wh + woff;
  const unsigned short* Wlb = Wl + woff;

  short8v ahA[4], alA[4], bhA[4], blA[4];
  short8v ahB[4], alB[4], bhB[4], blB[4];
#pragma unroll
  for (int i = 0; i < 4; ++i) {
    ahA[i] = *(const short8v*)(Ahb + (((size_t)i) << 14));
    alA[i] = *(const short8v*)(Alb + (((size_t)i) << 14));
    bhA[i] = *(const short8v*)(Whb + (((size_t)i) << 14));
    blA[i] = *(const short8v*)(Wlb + (((size_t)i) << 14));
  }

#pragma unroll
  for (int k0 = 0; k0 < 1024; k0 += 64) {
#pragma unroll
    for (int i = 0; i < 4; ++i) {
      ahB[i] = *(const short8v*)(Ahb + (((size_t)i) << 14) + k0 + 32);
      alB[i] = *(const short8v*)(Alb + (((size_t)i) << 14) + k0 + 32);
      bhB[i] = *(const short8v*)(Whb + (((size_t)i) << 14) + k0 + 32);
      blB[i] = *(const short8v*)(Wlb + (((size_t)i) << 14) + k0 + 32);
    }
#pragma unroll
    for (int i = 0; i < 4; ++i)
#pragma unroll
      for (int j = 0; j < 4; ++j) {
        acc[i][j] = __builtin_amdgcn_mfma_f32_16x16x32_bf16(ahA[i], bhA[j], acc[i][j], 0, 0, 0);
        acc[i][j] = __builtin_amdgcn_mfma_f32_16x16x32_bf16(ahA[i], blA[j], acc[i][j], 0, 0, 0);
        acc[i][j] = __builtin_amdgcn_mfma_f32_16x16x32_bf16(alA[i], bhA[j], acc[i][j], 0, 0, 0);
      }
    if (k0 + 64 < 1024) {
#pragma unroll
      for (int i = 0; i < 4; ++i) {
        ahA[i] = *(const short8v*)(Ahb + (((size_t)i) << 14) + k0 + 64);
        alA[i] = *(const short8v*)(Alb + (((size_t)i) << 14) + k0 + 64);
        bhA[i] = *(const short8v*)(Whb + (((size_t)i) << 14) + k0 + 64);
        blA[i] = *(const short8v*)(Wlb + (((size_t)i) << 14) + k0 + 64);
      }
    }
#pragma unroll
    for (int i = 0; i < 4; ++i)
#pragma unroll
      for (int j = 0; j < 4; ++j) {
        acc[i][j] = __builtin_amdgcn_mfma_f32_16x16x32_bf16(ahB[i], bhB[j], acc[i][j], 0, 0, 0);
        acc[i][j] = __builtin_amdgcn_mfma_f32_16x16x32_bf16(ahB[i], blB[j], acc[i][j], 0, 0, 0);
        acc[i][j] = __builtin_amdgcn_mfma_f32_16x16x32_bf16(alB[i], bhB[j], acc[i][j], 0, 0, 0);
      }
  }

#pragma unroll
  for (int i = 0; i < 4; ++i)
#pragma unroll
    for (int j = 0; j < 4; ++j)
#pragma unroll
      for (int rg = 0; rg < 4; ++rg) {
        int m = m0 + wr * 64 + i * 16 + (l >> 4) * 4 + rg;
        int n = n0 + wc * 64 + j * 16 + (l & 15);
        int b = m >> 11, t = m & (Tq - 1);
        int h = n >> 6, nn = n & 63;
        dst[((((size_t)b * Hq + h) * Tq + t) << 6) | nn] = acc[i][j][rg];
      }
}

// LN (optional) + token-shift + RoPE (optional). src in (B,H,T,N).
__global__ __launch_bounds__(256) void postproc(
    const float* __restrict__ src, float* __restrict__ dst,
    unsigned short* __restrict__ dst_bf,
    const float* __restrict__ lnw, const float* __restrict__ lnb,
    const float* __restrict__ xs_p, int doLNRope)
{
  const int w = threadIdx.x >> 6, lane = threadIdx.x & 63;
  const int row = blockIdx.x * 4 + w;
  const int t = row & (Tq - 1);
  const int h = (row >> 11) & (Hq - 1);
  const size_t base = (size_t)row << 6;
  const size_t pbase = (t > 0) ? base - 64 : base;
  float cur = src[base + lane];
  float prv = src[pbase + lane];
  if (doLNRope) {
    const float lw = lnw[lane], lb = lnb[lane];
    {
      float m = waveSum(cur) * (1.0f / 64.0f);
      float d = cur - m;
      float var = waveSum(d * d) * (1.0f / 64.0f);
      cur = d * rsqrtf(var + 1e-5f) * lw + lb;
    }
    {
      float m = waveSum(prv) * (1.0f / 64.0f);
      float d = prv - m;
      float var = waveSum(d * d) * (1.0f / 64.0f);
      prv = d * rsqrtf(var + 1e-5f) * lw + lb;
    }
  }
  const float xv = xs_p[h * 64 + lane];
  float val = cur + xv * (prv - cur);
  if (doLNRope) {
    float partner = __shfl_xor(val, 1);
    if (lane < 32) {
      int i = lane >> 1;
      float freq = (float)exp((double)i * (-log(10000.0) / 15.0));
      float th = (float)t * freq;
      float c = cosf(th), s = sinf(th);
      val = c * val + ((lane & 1) ? -s : s) * partner;
    }
  }
  if (dst) dst[base + lane] = val;
  if (dst_bf) dst_bf[base + lane] = f2bf(val);
}

__global__ __launch_bounds__(256) void kw_kernel(
    const float* __restrict__ x, const float* __restrict__ Wkw, float* __restrict__ out)
{
  const int bt = blockIdx.x;
  const int tid = threadIdx.x, w = tid >> 6, lane = tid & 63;
  __shared__ float xs[Cq];
  for (int i = tid; i < Cq; i += 256) xs[i] = x[(size_t)bt * Cq + i];
  __syncthreads();
  const int b = bt >> 11, t = bt & (Tq - 1);
  for (int h = w; h < Hq; h += 4) {
    float acc = 0.0f;
    for (int i = lane; i < Cq; i += 64) acc += xs[i] * Wkw[h * Cq + i];
    acc = waveSum(acc);
    if (lane == 0) out[((size_t)(b * Hq + h)) * Tq + t] = 1.0f / (1.0f + expf(-acc));
  }
}

// Phase A: state evolution, 64 blocks x 1024 threads. State in registers.
// Round-8 structure + count-gated scatter (deterministic int atomics).
__global__ __launch_bounds__(1024, 1) void state_evolve_kernel(
    const float* __restrict__ kf, const unsigned short* __restrict__ v_bf,
    const float* __restrict__ kwp,
    unsigned short* __restrict__ dkn_bf, unsigned short* __restrict__ vst_bf,
    float* __restrict__ cnt_snap,
    const float* __restrict__ lnw, const float* __restrict__ lnb)
{
  const int bh = blockIdx.x;
  const int tid = threadIdx.x;
  const int s = tid >> 2, qd = tid & 3;
  const int db = qd * 16;
  const size_t seq = (size_t)Tq * Nq;
  const float* kb_ = kf + (size_t)bh * seq;
  const unsigned short* vb_ = v_bf + (size_t)bh * seq;
  const float* kwb = kwp + (size_t)bh * Tq;

  __shared__ float dknT[32 * 260];          // [d-32][slot], k-major
  __shared__ float ck0T[32 * 260];          // [d-32][rc], k-major
  __shared__ unsigned short VRow[256 * 72]; // bf16 V window rows
  __shared__ float Ps[256], Qs[256], aS[256], kwS[256];
  __shared__ float lwS[64], lbS[64];
  __shared__ int best[256];
  __shared__ int cntS[256];

  if (tid < 64) { lwS[tid] = lnw[tid]; lbS[tid] = lnb[tid]; }

  float dkReg[16], dvReg[16];
#pragma unroll
  for (int i = 0; i < 16; ++i) { dkReg[i] = 0.f; dvReg[i] = 0.f; }
  float cnt = 0.f;
  __syncthreads();

  for (int c = 0; c < 8; ++c) {
    const int e = c * 256 + 256;
    const int bb = (e - 512 > 0) ? (e - 512) : 0;

    // ---- merged region: LN(d_k)+snapshots
    {
      float sum = 0.f;
#pragma unroll
      for (int i = 0; i < 16; ++i) sum += dkReg[i];
      sum += __shfl_xor(sum, 1); sum += __shfl_xor(sum, 2);
      const float mean = sum * (1.0f / 64.0f);
      float sq = 0.f;
#pragma unroll
      for (int i = 0; i < 16; ++i) { float d = dkReg[i] - mean; sq += d * d; }
      sq += __shfl_xor(sq, 1); sq += __shfl_xor(sq, 2);
      const float rs = rsqrtf(sq * (1.0f / 64.0f) + 1e-5f);
      float kn[16];
#pragma unroll
      for (int i = 0; i < 16; ++i)
        kn[i] = (dkReg[i] - mean) * rs * lwS[db + i] + lbS[db + i];
      unsigned int pk[8];
#pragma unroll
      for (int i2 = 0; i2 < 8; ++i2)
        pk[i2] = (unsigned)f2bf(kn[2 * i2]) | ((unsigned)f2bf(kn[2 * i2 + 1]) << 16);
      unsigned short* kd = dkn_bf + (((size_t)bh * 8 + c) << 14) + s * 64 + db;
      *(uint4*)kd = make_uint4(pk[0], pk[1], pk[2], pk[3]);
      *(uint4*)(kd + 8) = make_uint4(pk[4], pk[5], pk[6], pk[7]);

      if (c > 0 && c < 7) {
        if (qd >= 2) {
#pragma unroll
          for (int i = 0; i < 16; ++i) dknT[(db - 32 + i) * 260 + s] = kn[i];
        } else {
          float pp = 0.f, qq = 0.f;
#pragma unroll
          for (int i = 0; i < 16; ++i) {
            pp += kn[i] * lwS[db + i];
            qq += kn[i] * lbS[db + i];
          }
          pp += __shfl_xor(pp, 1);
          qq += __shfl_xor(qq, 1);
          if (qd == 0) { Ps[s] = pp; Qs[s] = qq; }
        }
      }

      float sqv = 0.f;
#pragma unroll
      for (int i = 0; i < 16; ++i) sqv += dvReg[i] * dvReg[i];
      sqv += __shfl_xor(sqv, 1); sqv += __shfl_xor(sqv, 2);
      const float inrm = 1.0f / fmaxf(sqrtf(sqv), 1e-12f);
#pragma unroll
      for (int i2 = 0; i2 < 8; ++i2)
        pk[i2] = (unsigned)f2bf(dvReg[2 * i2] * inrm) |
                 ((unsigned)f2bf(dvReg[2 * i2 + 1] * inrm) << 16);
      unsigned short* vd = vst_bf + (((size_t)bh * 8 + c) << 14) + s * 64 + db;
      *(uint4*)vd = make_uint4(pk[0], pk[1], pk[2], pk[3]);
      *(uint4*)(vd + 8) = make_uint4(pk[4], pk[5], pk[6], pk[7]);
      if (qd == 0) cnt_snap[((size_t)bh * 8 + c) * 256 + s] = cnt;
    }

    if (c == 7) break;

    // ---- ck0 LN + aS/kwS + V stage + best/cnt presets
    {
      float kv[16];
      if (qd >= 2) {
        const float* krow = kb_ + (size_t)(bb + s) * 64 + db;
#pragma unroll
        for (int i = 0; i < 16; i += 4) {
          float4 t4 = *(const float4*)(krow + i);
          kv[i] = t4.x; kv[i + 1] = t4.y; kv[i + 2] = t4.z; kv[i + 3] = t4.w;
        }
      } else {
#pragma unroll
        for (int i = 0; i < 16; ++i) kv[i] = 0.f;
      }
      float sum = 0.f;
#pragma unroll
      for (int i = 0; i < 16; ++i) sum += kv[i];
      sum += __shfl_xor(sum, 1); sum += __shfl_xor(sum, 2);
      const float mean = sum * (1.0f / 64.0f);
      float sq = 0.f;
#pragma unroll
      for (int i = 0; i < 16; ++i) { float d = kv[i] - mean; sq += d * d; }
      sq += __shfl_xor(sq, 1); sq += __shfl_xor(sq, 2);
      const float rs = rsqrtf(sq * (1.0f / 64.0f) + 1e-5f);
      if (qd >= 2) {
#pragma unroll
        for (int i = 0; i < 16; ++i)
          ck0T[(db - 32 + i) * 260 + s] =
              (kv[i] - mean) * rs * lwS[db + i] + lbS[db + i];
      }
      if (qd == 0) {
        aS[s] = (0.0f - mean) * rs;
        kwS[s] = kwb[bb + s];
      }
      const unsigned short* vsrc = vb_ + (size_t)(bb + s) * 64 + db;
      *(uint4*)&VRow[s * 72 + db] = *(const uint4*)vsrc;
      *(uint4*)&VRow[s * 72 + db + 8] = *(const uint4*)(vsrc + 8);
      if (tid < 256) {
        if (c == 0) { best[tid] = 1; cntS[tid] = (tid == 1) ? 256 : 0; }
        else cntS[tid] = 0;
      }
    }
    __syncthreads();

    // ---- sim + fused argmax (chunks 1..6)
    if (c > 0) {
      const int tx = tid & 31, ty = tid >> 5;
      const f32x4 pv0 = *(const f32x4*)&Ps[4 * tx];
      const f32x4 pv1 = *(const f32x4*)&Ps[128 + 4 * tx];
      const f32x4 qv0 = *(const f32x4*)&Qs[4 * tx];
      const f32x4 qv1 = *(const f32x4*)&Qs[128 + 4 * tx];
#pragma unroll
      for (int pass = 0; pass < 2; ++pass) {
        const int rc0 = pass * 128 + ty * 4;
        float a4[4];
#pragma unroll
        for (int i = 0; i < 4; ++i) a4[i] = aS[rc0 + i];
        float acc[4][8];
#pragma unroll
        for (int i = 0; i < 4; ++i)
#pragma unroll
          for (int j = 0; j < 4; ++j) {
            acc[i][j] = a4[i] * pv0[j] + qv0[j];
            acc[i][j + 4] = a4[i] * pv1[j] + qv1[j];
          }
#pragma unroll 4
        for (int k = 0; k < 32; ++k) {
          f32x4 av = *(const f32x4*)&ck0T[k * 260 + rc0];
          f32x4 b0 = *(const f32x4*)&dknT[k * 260 + 4 * tx];
          f32x4 b1 = *(const f32x4*)&dknT[k * 260 + 128 + 4 * tx];
#pragma unroll
          for (int i = 0; i < 4; ++i)
#pragma unroll
            for (int j = 0; j < 4; ++j) {
              acc[i][j] += av[i] * b0[j];
              acc[i][j + 4] += av[i] * b1[j];
            }
        }
#pragma unroll
        for (int i = 0; i < 4; ++i) {
          float bvv = -3.0e38f;
          int bi = 1 << 30;
#pragma unroll
          for (int j = 0; j < 8; ++j) {
            int s2 = (j < 4) ? (4 * tx + j) : (128 + 4 * tx + (j - 4));
            float v = acc[i][j];
            if (s2 == 0) v = -1.0e30f;  // SINK
            if (v > bvv || (v == bvv && s2 < bi)) { bvv = v; bi = s2; }
          }
#pragma unroll
          for (int o = 16; o; o >>= 1) {
            float ov = __shfl_xor(bvv, o);
            int oi = __shfl_xor(bi, o);
            if (ov > bvv || (ov == bvv && oi < bi)) { bvv = ov; bi = oi; }
          }
          if (tx == 0) {
            best[rc0 + i] = bi;
            atomicAdd(&cntS[bi], 1);
          }
        }
      }
      __syncthreads();
    }

    // ---- ownership scatter into registers (count-gated, early-exit)
    {
      const int need = cntS[s];
      if (need) {
        int found = 0;
        for (int rc = 0; rc < 256 && found < need; ++rc) {
          if (best[rc] == s) {
            const float kwv = kwS[rc];
            if (qd < 2) {
              const float a = aS[rc];
#pragma unroll
              for (int i = 0; i < 16; ++i)
                dkReg[i] += (a * lwS[db + i] + lbS[db + i]) * kwv;
            } else {
#pragma unroll
              for (int i = 0; i < 16; ++i)
                dkReg[i] += ck0T[(db - 32 + i) * 260 + rc] * kwv;
            }
            const uint4 u0 = *(const uint4*)&VRow[rc * 72 + db];
            const uint4 u1 = *(const uint4*)&VRow[rc * 72 + db + 8];
            const unsigned uu[8] = {u0.x, u0.y, u0.z, u0.w, u1.x, u1.y, u1.z, u1.w};
#pragma unroll
            for (int i2 = 0; i2 < 8; ++i2) {
              dvReg[2 * i2] += __uint_as_float((uu[i2] & 0xFFFFu) << 16) * kwv;
              dvReg[2 * i2 + 1] += __uint_as_float(uu[i2] & 0xFFFF0000u) * kwv;
            }
            ++found;
          }
        }
        cnt += (float)need;
      }
    }
    __syncthreads();
  }
}

// Phase B: MFMA flash attention. Grid 1024 = (bh, c, half); 256 thr, 4 waves x 32 rows.
__global__ __launch_bounds__(256, 2) void attn_mfma_kernel(
    const unsigned short* __restrict__ q_bf, const unsigned short* __restrict__ k_bf,
    const unsigned short* __restrict__ v_bf,
    const unsigned short* __restrict__ dkn_bf, const unsigned short* __restrict__ vst_bf,
    const float* __restrict__ cnt_snap, float* __restrict__ y,
    const float* __restrict__ ftp, const float* __restrict__ stp)
{
  const int blk = blockIdx.x;
  const int bh = blk >> 4;
  const int c = (blk >> 1) & 7;
  const int half = blk & 1;
  const int h = bh & (Hq - 1);
  const int tid = threadIdx.x;
  const int w = tid >> 6, l = tid & 63;
  const int g = l >> 4, n = l & 15;
  const int rows0 = c * 256 + half * 128 + w * 32;
  const int e = c * 256 + 256;
  const int bb = (e - 512 > 0) ? (e - 512) : 0;
  const int nwt = (e - bb) >> 6;  // 4 or 8
  const float stsc = stp[h] * 0.125f, ftsc = ftp[h] * 0.125f;
  const size_t seq = (size_t)Tq * Nq;

  __shared__ unsigned short Ks[64 * 72];
  __shared__ unsigned short VTs[64 * 72];
  __shared__ unsigned short Ps[4][32 * 72];
  __shared__ float wts[64];

  short8v qf[2][2];
#pragma unroll
  for (int mt = 0; mt < 2; ++mt)
#pragma unroll
    for (int kh = 0; kh < 2; ++kh)
      qf[mt][kh] = *(const short8v*)(q_bf + (size_t)bh * seq +
                                     (size_t)(rows0 + mt * 16 + n) * 64 + kh * 32 + g * 8);

  f32x4 oacc[2][4];
#pragma unroll
  for (int mt = 0; mt < 2; ++mt)
#pragma unroll
    for (int dt = 0; dt < 4; ++dt) oacc[mt][dt] = (f32x4){0.f, 0.f, 0.f, 0.f};
  float rowM[2][4], rowL[2][4];
#pragma unroll
  for (int mt = 0; mt < 2; ++mt)
#pragma unroll
    for (int r = 0; r < 4; ++r) { rowM[mt][r] = -1.0e30f; rowL[mt][r] = 0.f; }

  const int nkt = 4 + nwt;
  for (int kt = 0; kt < nkt; ++kt) {
    const bool isState = kt < 4;
    const int t0 = isState ? kt * 64 : bb + (kt - 4) * 64;
    const unsigned short* ksrc = isState
        ? dkn_bf + (((size_t)bh * 8 + c) << 14) + (size_t)t0 * 64
        : k_bf + (size_t)bh * seq + (size_t)t0 * 64;
    const unsigned short* vsrc = isState
        ? vst_bf + (((size_t)bh * 8 + c) << 14) + (size_t)t0 * 64
        : v_bf + (size_t)bh * seq + (size_t)t0 * 64;

    __syncthreads();
    {
      const int row = tid >> 2, q4 = tid & 3;
      const unsigned short* src = ksrc + row * 64 + q4 * 16;
      *(uint4*)&Ks[row * 72 + q4 * 16] = *(const uint4*)src;
      *(uint4*)&Ks[row * 72 + q4 * 16 + 8] = *(const uint4*)(src + 8);
      const unsigned short* vs = vsrc + row * 64 + q4 * 16;
#pragma unroll
      for (int i = 0; i < 16; ++i) VTs[(q4 * 16 + i) * 72 + row] = vs[i];
      if (tid < 64)
        wts[tid] = isState ? cnt_snap[((size_t)bh * 8 + c) * 256 + kt * 64 + tid] : 1.0f;
    }
    __syncthreads();

    f32x4 sacc[2][4];
#pragma unroll
    for (int mt = 0; mt < 2; ++mt)
#pragma unroll
      for (int nt = 0; nt < 4; ++nt) sacc[mt][nt] = (f32x4){0.f, 0.f, 0.f, 0.f};
#pragma unroll
    for (int nt = 0; nt < 4; ++nt) {
      short8v kf0 = *(const short8v*)&Ks[(nt * 16 + n) * 72 + g * 8];
      short8v kf1 = *(const short8v*)&Ks[(nt * 16 + n) * 72 + 32 + g * 8];
#pragma unroll
      for (int mt = 0; mt < 2; ++mt) {
        sacc[mt][nt] = __builtin_amdgcn_mfma_f32_16x16x32_bf16(qf[mt][0], kf0, sacc[mt][nt], 0, 0, 0);
        sacc[mt][nt] = __builtin_amdgcn_mfma_f32_16x16x32_bf16(qf[mt][1], kf1, sacc[mt][nt], 0, 0, 0);
      }
    }

    const float scale = isState ? stsc : ftsc;
    float wt_n[4];
#pragma unroll
    for (int nt = 0; nt < 4; ++nt) wt_n[nt] = wts[nt * 16 + n];

#pragma unroll
    for (int mt = 0; mt < 2; ++mt) {
#pragma unroll
      for (int r = 0; r < 4; ++r) {
        float sv[4];
#pragma unroll
        for (int nt = 0; nt < 4; ++nt) {
          float s = sacc[mt][nt][r] * scale;
          if (!isState) {
            int qi = rows0 + mt * 16 + g * 4 + r;
            int kj = t0 + nt * 16 + n;
            if (kj > qi) s = -1.0e30f;
          }
          sv[nt] = s;
        }
        float tmax = fmaxf(fmaxf(sv[0], sv[1]), fmaxf(sv[2], sv[3]));
        tmax = fmaxf(tmax, __shfl_xor(tmax, 1));
        tmax = fmaxf(tmax, __shfl_xor(tmax, 2));
        tmax = fmaxf(tmax, __shfl_xor(tmax, 4));
        tmax = fmaxf(tmax, __shfl_xor(tmax, 8));
        const float Mold = rowM[mt][r];
        const float Mnew = fmaxf(Mold, tmax);
        const float al = __expf(Mold - Mnew);
        rowM[mt][r] = Mnew;
        float p[4], ts = 0.f;
#pragma unroll
        for (int nt = 0; nt < 4; ++nt) { p[nt] = __expf(sv[nt] - Mnew); ts += p[nt]; }
        ts += __shfl_xor(ts, 1);
        ts += __shfl_xor(ts, 2);
        ts += __shfl_xor(ts, 4);
        ts += __shfl_xor(ts, 8);
        rowL[mt][r] = rowL[mt][r] * al + ts;
#pragma unroll
        for (int dt = 0; dt < 4; ++dt) oacc[mt][dt][r] *= al;
        const int prow = (mt * 16 + g * 4 + r) * 72;
#pragma unroll
        for (int nt = 0; nt < 4; ++nt)
          Ps[w][prow + nt * 16 + n] = f2bf(p[nt] * wt_n[nt]);
      }
    }

    short8v pf[2][2];
#pragma unroll
    for (int mt = 0; mt < 2; ++mt)
#pragma unroll
      for (int jh = 0; jh < 2; ++jh)
        pf[mt][jh] = *(const short8v*)&Ps[w][(mt * 16 + n) * 72 + jh * 32 + g * 8];
#pragma unroll
    for (int dt = 0; dt < 4; ++dt) {
      short8v vf0 = *(const short8v*)&VTs[(dt * 16 + n) * 72 + g * 8];
      short8v vf1 = *(const short8v*)&VTs[(dt * 16 + n) * 72 + 32 + g * 8];
#pragma unroll
      for (int mt = 0; mt < 2; ++mt) {
        oacc[mt][dt] = __builtin_amdgcn_mfma_f32_16x16x32_bf16(pf[mt][0], vf0, oacc[mt][dt], 0, 0, 0);
        oacc[mt][dt] = __builtin_amdgcn_mfma_f32_16x16x32_bf16(pf[mt][1], vf1, oacc[mt][dt], 0, 0, 0);
      }
    }
  }

#pragma unroll
  for (int mt = 0; mt < 2; ++mt) {
#pragma unroll
    for (int r = 0; r < 4; ++r) {
      const float inv = 1.0f / rowL[mt][r];
      const int row = rows0 + mt * 16 + g * 4 + r;
#pragma unroll
      for (int dt = 0; dt < 4; ++dt)
        y[(size_t)bh * seq + (size_t)row * 64 + dt * 16 + n] = oacc[mt][dt][r] * inv;
    }
  }
}

// LN over C=1024 per (b,t); gathers from (B,H,T,N), writes bf16 (B,T,C)
__global__ __launch_bounds__(256) void final_ln(
    const float* __restrict__ y, const float* __restrict__ lnw,
    const float* __restrict__ lnb, unsigned short* __restrict__ dst)
{
  const int bt = blockIdx.x;
  const int b = bt >> 11, t = bt & (Tq - 1);
  const int tid = threadIdx.x, w = tid >> 6, lane = tid & 63;
  __shared__ float red[8];
  float v[4];
  float s = 0.0f;
#pragma unroll
  for (int i = 0; i < 4; ++i) {
    int c = tid + (i << 8);
    int h = c >> 6, n = c & 63;
    v[i] = y[((((size_t)b * Hq + h) * Tq + t) << 6) + n];
    s += v[i];
  }
  s = waveSum(s);
  if (lane == 0) red[w] = s;
  __syncthreads();
  const float mean = (red[0] + red[1] + red[2] + red[3]) * (1.0f / 1024.0f);
  float s2 = 0.0f;
#pragma unroll
  for (int i = 0; i < 4; ++i) { float d = v[i] - mean; s2 += d * d; }
  s2 = waveSum(s2);
  if (lane == 0) red[4 + w] = s2;
  __syncthreads();
  const float var = (red[4] + red[5] + red[6] + red[7]) * (1.0f / 1024.0f);
  const float rs = rsqrtf(var + 1e-5f);
#pragma unroll
  for (int i = 0; i < 4; ++i) {
    int c = tid + (i << 8);
    dst[(size_t)bt * Cq + c] = f2bf((v[i] - mean) * rs * lnw[c] + lnb[c]);
  }
}

extern "C" void kernel_launch(void* const* d_in, const int* in_sizes, int n_in,
                              void* d_out, int out_size, void* d_ws, size_t ws_size,
                              hipStream_t stream)
{
  (void)in_sizes; (void)n_in; (void)out_size; (void)ws_size;
  const float* residual = (const float*)d_in[0];
  const float* x        = (const float*)d_in[1];
  const float* v1       = (const float*)d_in[2];
  const float* Wq       = (const float*)d_in[6];
  const float* Wk       = (const float*)d_in[7];
  const float* Wv       = (const float*)d_in[8];
  const float* Wproj    = (const float*)d_in[9];
  const float* Wkw      = (const float*)d_in[10];
  const float* x_q      = (const float*)d_in[11];
  const float* x_k      = (const float*)d_in[12];
  const float* x_v      = (const float*)d_in[13];
  const float* lamb     = (const float*)d_in[14];
  const float* ln_q_w   = (const float*)d_in[15];
  const float* ln_q_b   = (const float*)d_in[16];
  const float* ln_k_w   = (const float*)d_in[17];
  const float* ln_k_b   = (const float*)d_in[18];
  const float* ln_dk_w  = (const float*)d_in[19];
  const float* ln_dk_b  = (const float*)d_in[20];
  const float* ln_res_w = (const float*)d_in[21];
  const float* ln_res_b = (const float*)d_in[22];
  const float* ftp      = (const float*)d_in[23];
  const float* stp      = (const float*)d_in[24];

  float* ws = (float*)d_ws;
  const size_t SZ = (size_t)Bq * Hq * Tq * Nq;  // 8388608
  float* q_raw = ws;
  float* ybuf  = ws;
  float* k_raw = ws + SZ;
  unsigned short* vst_bf = (unsigned short*)(ws + SZ);
  float* cnt_snap = ws + SZ + SZ / 2;
  float* v_mix = ws + 2 * SZ;
  unsigned short* ylnb_bf = (unsigned short*)(ws + 2 * SZ);
  float* k_fin = ws + 3 * SZ;
  unsigned short* q_bf = (unsigned short*)(ws + 4 * SZ);
  unsigned short* x_lo = q_bf;
  unsigned short* k_bf = q_bf + SZ;
  unsigned short* wk_hi = k_bf;
  unsigned short* wk_lo = wk_hi + (1u << 20);
  unsigned short* v_bf = (unsigned short*)(ws + 5 * SZ);
  unsigned short* xb   = v_bf + SZ;
  unsigned short* dkn_bf = xb;
  unsigned short* wqb = (unsigned short*)(ws + 6 * SZ);
  unsigned short* wvb = wqb + (1u << 20);
  unsigned short* wpb = wvb + (1u << 20);
  float* kwbuf = ws + 6 * SZ + ((3u << 20) >> 1);

  dim3 gb(256);
  dim3 ggb(64, 8);

  hipLaunchKernelGGL(f32_to_bf16_hilo_kernel, dim3((int)(SZ / 4 / 256)), gb, 0, stream,
                     x, xb, x_lo, (int)(SZ / 4));
  hipLaunchKernelGGL(f32_to_bf16_hilo_kernel, dim3(1024), gb, 0, stream,
                     Wk, wk_hi, wk_lo, 262144);
  hipLaunchKernelGGL(f32_to_bf16_kernel, dim3(1024), gb, 0, stream, Wq, wqb, 262144);
  hipLaunchKernelGGL(f32_to_bf16_kernel, dim3(1024), gb, 0, stream, Wv, wvb, 262144);
  hipLaunchKernelGGL(f32_to_bf16_kernel, dim3(1024), gb, 0, stream, Wproj, wpb, 262144);

  hipLaunchKernelGGL(gemm_bf16, ggb, gb, 0, stream, xb, wqb, q_raw, (const float*)nullptr, lamb, 1);
  hipLaunchKernelGGL(gemm_bf16_split, ggb, gb, 0, stream, xb, x_lo, wk_hi, wk_lo, k_raw);
  hipLaunchKernelGGL(gemm_bf16, ggb, gb, 0, stream, xb, wvb, v_mix, v1, lamb, 2);
  hipLaunchKernelGGL(kw_kernel, dim3(Bq * Tq), gb, 0, stream, x, Wkw, kwbuf);

  const int rows = Bq * Hq * Tq;
  hipLaunchKernelGGL(postproc, dim3(rows / 4), gb, 0, stream, q_raw, (float*)nullptr, q_bf, ln_q_w, ln_q_b, x_q, 1);
  hipLaunchKernelGGL(postproc, dim3(rows / 4), gb, 0, stream, k_raw, k_fin, k_bf, ln_k_w, ln_k_b, x_k, 1);
  hipLaunchKernelGGL(postproc, dim3(rows / 4), gb, 0, stream, v_mix, (float*)nullptr, v_bf,
                     (const float*)nullptr, (const float*)nullptr, x_v, 0);

  hipLaunchKernelGGL(state_evolve_kernel, dim3(Bq * Hq), dim3(1024), 0, stream,
                     k_fin, v_bf, kwbuf, dkn_bf, vst_bf, cnt_snap, ln_dk_w, ln_dk_b);

  hipLaunchKernelGGL(attn_mfma_kernel, dim3(Bq * Hq * 16), gb, 0, stream,
                     q_bf, k_bf, v_bf, dkn_bf, vst_bf, cnt_snap, ybuf, ftp, stp);

  hipLaunchKernelGGL(final_ln, dim3(Bq * Tq), gb, 0, stream, ybuf, ln_res_w, ln_res_b, ylnb_bf);
  hipLaunchKernelGGL(gemm_bf16, ggb, gb, 0, stream, ylnb_bf, wpb, (float*)d_out, residual, lamb, 3);
}

// Round 12
// 1380.769 us; speedup vs baseline: 1.4360x; 1.0937x over previous
//
#include <hip/hip_runtime.h>
#include <math.h>

#define Bq 4
#define Tq 2048
#define Cq 1024
#define Hq 16
#define Nq 64

typedef __attribute__((ext_vector_type(8))) short short8v;
typedef __attribute__((ext_vector_type(4))) float f32x4;

__device__ inline float waveSum(float v) {
#pragma unroll
  for (int o = 32; o; o >>= 1) v += __shfl_xor(v, o);
  return v;
}
__device__ inline unsigned short f2bf(float f) {
  unsigned u = __float_as_uint(f);
  unsigned r = (u + 0x7FFFu + ((u >> 16) & 1u)) >> 16;
  return (unsigned short)r;
}
__device__ inline float bf2f(unsigned short b) {
  return __uint_as_float(((unsigned)b) << 16);
}

__global__ __launch_bounds__(256) void f32_to_bf16_kernel(
    const float* __restrict__ src, unsigned short* __restrict__ dst, int n4)
{
  int i = blockIdx.x * 256 + threadIdx.x;
  if (i >= n4) return;
  float4 v = ((const float4*)src)[i];
  ushort4 o;
  o.x = f2bf(v.x); o.y = f2bf(v.y); o.z = f2bf(v.z); o.w = f2bf(v.w);
  ((ushort4*)dst)[i] = o;
}

__global__ __launch_bounds__(256) void f32_to_bf16_hilo_kernel(
    const float* __restrict__ src, unsigned short* __restrict__ hi,
    unsigned short* __restrict__ lo, int n4)
{
  int i = blockIdx.x * 256 + threadIdx.x;
  if (i >= n4) return;
  float4 v = ((const float4*)src)[i];
  ushort4 h, l;
  h.x = f2bf(v.x); l.x = f2bf(v.x - bf2f(h.x));
  h.y = f2bf(v.y); l.y = f2bf(v.y - bf2f(h.y));
  h.z = f2bf(v.z); l.z = f2bf(v.z - bf2f(h.z));
  h.w = f2bf(v.w); l.w = f2bf(v.w - bf2f(h.w));
  ((ushort4*)hi)[i] = h;
  ((ushort4*)lo)[i] = l;
}

// ---- bf16 MFMA GEMM (plain) ----
__global__ __launch_bounds__(256) void gemm_bf16(
    const unsigned short* __restrict__ A, const unsigned short* __restrict__ W,
    float* __restrict__ dst, const float* __restrict__ extra,
    const float* __restrict__ lamb_p, int mode)
{
  const int m0 = blockIdx.x * 128, n0 = blockIdx.y * 128;
  const int tid = threadIdx.x;
  const int w = tid >> 6, l = tid & 63;
  const int wr = w >> 1, wc = w & 1;
  const int lrow = l & 15;
  const int lk = (l >> 4) * 8;

  f32x4 acc[4][4];
#pragma unroll
  for (int i = 0; i < 4; ++i)
#pragma unroll
    for (int j = 0; j < 4; ++j) acc[i][j] = (f32x4){0.f, 0.f, 0.f, 0.f};

  const unsigned short* Ab = A + (((size_t)(m0 + wr * 64 + lrow)) << 10) + lk;
  const unsigned short* Wb = W + (((size_t)(n0 + wc * 64 + lrow)) << 10) + lk;

  for (int k0 = 0; k0 < 1024; k0 += 32) {
    short8v a[4], b[4];
#pragma unroll
    for (int i = 0; i < 4; ++i) a[i] = *(const short8v*)(Ab + (((size_t)i) << 14) + k0);
#pragma unroll
    for (int j = 0; j < 4; ++j) b[j] = *(const short8v*)(Wb + (((size_t)j) << 14) + k0);
#pragma unroll
    for (int i = 0; i < 4; ++i)
#pragma unroll
      for (int j = 0; j < 4; ++j)
        acc[i][j] = __builtin_amdgcn_mfma_f32_16x16x32_bf16(a[i], b[j], acc[i][j], 0, 0, 0);
  }

  const float lam = (mode == 2) ? lamb_p[0] : 0.0f;
#pragma unroll
  for (int i = 0; i < 4; ++i)
#pragma unroll
    for (int j = 0; j < 4; ++j)
#pragma unroll
      for (int rg = 0; rg < 4; ++rg) {
        int m = m0 + wr * 64 + i * 16 + (l >> 4) * 4 + rg;
        int n = n0 + wc * 64 + j * 16 + (l & 15);
        float v = acc[i][j][rg];
        if (mode == 3) {
          dst[(size_t)m * Cq + n] = v + extra[(size_t)m * Cq + n];
        } else {
          if (mode == 2) v = (1.0f - lam) * v + lam * extra[(size_t)m * Cq + n];
          int b = m >> 11, t = m & (Tq - 1);
          int h = n >> 6, nn = n & 63;
          dst[((((size_t)b * Hq + h) * Tq + t) << 6) | nn] = v;
        }
      }
}

// ---- split-precision bf16 MFMA GEMM (K path) ----
__global__ __launch_bounds__(256) void gemm_bf16_split(
    const unsigned short* __restrict__ Ah, const unsigned short* __restrict__ Al,
    const unsigned short* __restrict__ Wh, const unsigned short* __restrict__ Wl,
    float* __restrict__ dst)
{
  const int m0 = blockIdx.x * 128, n0 = blockIdx.y * 128;
  const int tid = threadIdx.x;
  const int w = tid >> 6, l = tid & 63;
  const int wr = w >> 1, wc = w & 1;
  const int lrow = l & 15;
  const int lk = (l >> 4) * 8;

  f32x4 acc[4][4];
#pragma unroll
  for (int i = 0; i < 4; ++i)
#pragma unroll
    for (int j = 0; j < 4; ++j) acc[i][j] = (f32x4){0.f, 0.f, 0.f, 0.f};

  const size_t aoff = (((size_t)(m0 + wr * 64 + lrow)) << 10) + lk;
  const size_t woff = (((size_t)(n0 + wc * 64 + lrow)) << 10) + lk;
  const unsigned short* Ahb = Ah + aoff;
  const unsigned short* Alb = Al + aoff;
  const unsigned short* Whb = Wh + woff;
  const unsigned short* Wlb = Wl + woff;

  for (int k0 = 0; k0 < 1024; k0 += 32) {
    short8v ah[4], al[4], bh[4], bl[4];
#pragma unroll
    for (int i = 0; i < 4; ++i) {
      ah[i] = *(const short8v*)(Ahb + (((size_t)i) << 14) + k0);
      al[i] = *(const short8v*)(Alb + (((size_t)i) << 14) + k0);
    }
#pragma unroll
    for (int j = 0; j < 4; ++j) {
      bh[j] = *(const short8v*)(Whb + (((size_t)j) << 14) + k0);
      bl[j] = *(const short8v*)(Wlb + (((size_t)j) << 14) + k0);
    }
#pragma unroll
    for (int i = 0; i < 4; ++i)
#pragma unroll
      for (int j = 0; j < 4; ++j) {
        acc[i][j] = __builtin_amdgcn_mfma_f32_16x16x32_bf16(ah[i], bh[j], acc[i][j], 0, 0, 0);
        acc[i][j] = __builtin_amdgcn_mfma_f32_16x16x32_bf16(ah[i], bl[j], acc[i][j], 0, 0, 0);
        acc[i][j] = __builtin_amdgcn_mfma_f32_16x16x32_bf16(al[i], bh[j], acc[i][j], 0, 0, 0);
      }
  }

#pragma unroll
  for (int i = 0; i < 4; ++i)
#pragma unroll
    for (int j = 0; j < 4; ++j)
#pragma unroll
      for (int rg = 0; rg < 4; ++rg) {
        int m = m0 + wr * 64 + i * 16 + (l >> 4) * 4 + rg;
        int n = n0 + wc * 64 + j * 16 + (l & 15);
        int b = m >> 11, t = m & (Tq - 1);
        int h = n >> 6, nn = n & 63;
        dst[((((size_t)b * Hq + h) * Tq + t) << 6) | nn] = acc[i][j][rg];
      }
}

// LN (optional) + token-shift + RoPE (optional). src in (B,H,T,N).
__global__ __launch_bounds__(256) void postproc(
    const float* __restrict__ src, float* __restrict__ dst,
    unsigned short* __restrict__ dst_bf,
    const float* __restrict__ lnw, const float* __restrict__ lnb,
    const float* __restrict__ xs_p, int doLNRope)
{
  const int w = threadIdx.x >> 6, lane = threadIdx.x & 63;
  const int row = blockIdx.x * 4 + w;
  const int t = row & (Tq - 1);
  const int h = (row >> 11) & (Hq - 1);
  const size_t base = (size_t)row << 6;
  const size_t pbase = (t > 0) ? base - 64 : base;
  float cur = src[base + lane];
  float prv = src[pbase + lane];
  if (doLNRope) {
    const float lw = lnw[lane], lb = lnb[lane];
    {
      float m = waveSum(cur) * (1.0f / 64.0f);
      float d = cur - m;
      float var = waveSum(d * d) * (1.0f / 64.0f);
      cur = d * rsqrtf(var + 1e-5f) * lw + lb;
    }
    {
      float m = waveSum(prv) * (1.0f / 64.0f);
      float d = prv - m;
      float var = waveSum(d * d) * (1.0f / 64.0f);
      prv = d * rsqrtf(var + 1e-5f) * lw + lb;
    }
  }
  const float xv = xs_p[h * 64 + lane];
  float val = cur + xv * (prv - cur);
  if (doLNRope) {
    float partner = __shfl_xor(val, 1);
    if (lane < 32) {
      int i = lane >> 1;
      float freq = (float)exp((double)i * (-log(10000.0) / 15.0));
      float th = (float)t * freq;
      float c = cosf(th), s = sinf(th);
      val = c * val + ((lane & 1) ? -s : s) * partner;
    }
  }
  if (dst) dst[base + lane] = val;
  if (dst_bf) dst_bf[base + lane] = f2bf(val);
}

__global__ __launch_bounds__(256) void kw_kernel(
    const float* __restrict__ x, const float* __restrict__ Wkw, float* __restrict__ out)
{
  const int bt = blockIdx.x;
  const int tid = threadIdx.x, w = tid >> 6, lane = tid & 63;
  __shared__ float xs[Cq];
  for (int i = tid; i < Cq; i += 256) xs[i] = x[(size_t)bt * Cq + i];
  __syncthreads();
  const int b = bt >> 11, t = bt & (Tq - 1);
  for (int h = w; h < Hq; h += 4) {
    float acc = 0.0f;
    for (int i = lane; i < Cq; i += 64) acc += xs[i] * Wkw[h * Cq + i];
    acc = waveSum(acc);
    if (lane == 0) out[((size_t)(b * Hq + h)) * Tq + t] = 1.0f / (1.0f + expf(-acc));
  }
}

// Phase A: state evolution, 64 blocks x 1024 threads. Round-7 structure,
// + chunk-0 sim skip (provably argmax==1) + int4 scan of best[].
__global__ __launch_bounds__(1024, 1) void state_evolve_kernel(
    const float* __restrict__ kf, const unsigned short* __restrict__ v_bf,
    const float* __restrict__ kwp,
    unsigned short* __restrict__ dkn_bf, unsigned short* __restrict__ vst_bf,
    float* __restrict__ cnt_snap,
    const float* __restrict__ lnw, const float* __restrict__ lnb)
{
  const int bh = blockIdx.x;
  const int tid = threadIdx.x;
  const int s = tid >> 2, qd = tid & 3;
  const int db = qd * 16;
  const size_t seq = (size_t)Tq * Nq;
  const float* kb_ = kf + (size_t)bh * seq;
  const unsigned short* vb_ = v_bf + (size_t)bh * seq;
  const float* kwb = kwp + (size_t)bh * Tq;

  __shared__ float dknT[32 * 260];          // [d-32][slot], k-major
  __shared__ float ck0T[32 * 260];          // [d-32][rc], k-major
  __shared__ unsigned short VRow[256 * 72]; // bf16 V window rows
  __shared__ float Ps[256], Qs[256], aS[256], kwS[256];
  __shared__ float lwS[64], lbS[64];
  __shared__ int best[256];

  if (tid < 64) { lwS[tid] = lnw[tid]; lbS[tid] = lnb[tid]; }

  float dkReg[16], dvReg[16];
#pragma unroll
  for (int i = 0; i < 16; ++i) { dkReg[i] = 0.f; dvReg[i] = 0.f; }
  float cnt = 0.f;
  __syncthreads();

  for (int c = 0; c < 8; ++c) {
    const int e = c * 256 + 256;
    const int bb = (e - 512 > 0) ? (e - 512) : 0;

    // ---- phase A: LN(d_k) -> snapshot + dknT/P/Q; v_state snapshot; cnt
    {
      float sum = 0.f;
#pragma unroll
      for (int i = 0; i < 16; ++i) sum += dkReg[i];
      sum += __shfl_xor(sum, 1); sum += __shfl_xor(sum, 2);
      const float mean = sum * (1.0f / 64.0f);
      float sq = 0.f;
#pragma unroll
      for (int i = 0; i < 16; ++i) { float d = dkReg[i] - mean; sq += d * d; }
      sq += __shfl_xor(sq, 1); sq += __shfl_xor(sq, 2);
      const float rs = rsqrtf(sq * (1.0f / 64.0f) + 1e-5f);
      float kn[16];
#pragma unroll
      for (int i = 0; i < 16; ++i)
        kn[i] = (dkReg[i] - mean) * rs * lwS[db + i] + lbS[db + i];
      unsigned int pk[8];
#pragma unroll
      for (int i2 = 0; i2 < 8; ++i2)
        pk[i2] = (unsigned)f2bf(kn[2 * i2]) | ((unsigned)f2bf(kn[2 * i2 + 1]) << 16);
      unsigned short* kd = dkn_bf + (((size_t)bh * 8 + c) << 14) + s * 64 + db;
      *(uint4*)kd = make_uint4(pk[0], pk[1], pk[2], pk[3]);
      *(uint4*)(kd + 8) = make_uint4(pk[4], pk[5], pk[6], pk[7]);

      if (c > 0 && c < 7) {
        if (qd >= 2) {
#pragma unroll
          for (int i = 0; i < 16; ++i) dknT[(db - 32 + i) * 260 + s] = kn[i];
        } else {
          float pp = 0.f, qq = 0.f;
#pragma unroll
          for (int i = 0; i < 16; ++i) {
            pp += kn[i] * lwS[db + i];
            qq += kn[i] * lbS[db + i];
          }
          pp += __shfl_xor(pp, 1);
          qq += __shfl_xor(qq, 1);
          if (qd == 0) { Ps[s] = pp; Qs[s] = qq; }
        }
      }

      float sqv = 0.f;
#pragma unroll
      for (int i = 0; i < 16; ++i) sqv += dvReg[i] * dvReg[i];
      sqv += __shfl_xor(sqv, 1); sqv += __shfl_xor(sqv, 2);
      const float inrm = 1.0f / fmaxf(sqrtf(sqv), 1e-12f);
#pragma unroll
      for (int i2 = 0; i2 < 8; ++i2)
        pk[i2] = (unsigned)f2bf(dvReg[2 * i2] * inrm) |
                 ((unsigned)f2bf(dvReg[2 * i2 + 1] * inrm) << 16);
      unsigned short* vd = vst_bf + (((size_t)bh * 8 + c) << 14) + s * 64 + db;
      *(uint4*)vd = make_uint4(pk[0], pk[1], pk[2], pk[3]);
      *(uint4*)(vd + 8) = make_uint4(pk[4], pk[5], pk[6], pk[7]);
      if (qd == 0) cnt_snap[((size_t)bh * 8 + c) * 256 + s] = cnt;
    }

    if (c == 7) break;

    // ---- phase B: ck0 LN + aS/kwS + V stage (+ chunk-0 best preset)
    {
      float kv[16];
      if (qd >= 2) {
        const float* krow = kb_ + (size_t)(bb + s) * 64 + db;
#pragma unroll
        for (int i = 0; i < 16; i += 4) {
          float4 t4 = *(const float4*)(krow + i);
          kv[i] = t4.x; kv[i + 1] = t4.y; kv[i + 2] = t4.z; kv[i + 3] = t4.w;
        }
      } else {
#pragma unroll
        for (int i = 0; i < 16; ++i) kv[i] = 0.f;
      }
      float sum = 0.f;
#pragma unroll
      for (int i = 0; i < 16; ++i) sum += kv[i];
      sum += __shfl_xor(sum, 1); sum += __shfl_xor(sum, 2);
      const float mean = sum * (1.0f / 64.0f);
      float sq = 0.f;
#pragma unroll
      for (int i = 0; i < 16; ++i) { float d = kv[i] - mean; sq += d * d; }
      sq += __shfl_xor(sq, 1); sq += __shfl_xor(sq, 2);
      const float rs = rsqrtf(sq * (1.0f / 64.0f) + 1e-5f);
      if (qd >= 2) {
#pragma unroll
        for (int i = 0; i < 16; ++i)
          ck0T[(db - 32 + i) * 260 + s] =
              (kv[i] - mean) * rs * lwS[db + i] + lbS[db + i];
      }
      if (qd == 0) {
        aS[s] = (0.0f - mean) * rs;
        kwS[s] = kwb[bb + s];
      }
      const unsigned short* vsrc = vb_ + (size_t)(bb + s) * 64 + db;
      *(uint4*)&VRow[s * 72 + db] = *(const uint4*)vsrc;
      *(uint4*)&VRow[s * 72 + db + 8] = *(const uint4*)(vsrc + 8);
      // chunk 0: zero state -> all dkn rows identical -> sim ties -> argmax = 1
      if (c == 0 && tid < 256) best[tid] = 1;
    }
    __syncthreads();

    // ---- phase C: sim + fused argmax (chunks 1..6)
    if (c > 0) {
      const int tx = tid & 31, ty = tid >> 5;
#pragma unroll
      for (int pass = 0; pass < 2; ++pass) {
        const int rc0 = pass * 128 + ty * 8;
        float a4[8];
#pragma unroll
        for (int i = 0; i < 8; ++i) a4[i] = aS[rc0 + i];
        float acc[8][8];
#pragma unroll
        for (int j = 0; j < 8; ++j) {
          const float pj = Ps[tx + 32 * j], qj = Qs[tx + 32 * j];
#pragma unroll
          for (int i = 0; i < 8; ++i) acc[i][j] = a4[i] * pj + qj;
        }
        // NOTE: r7 used 4-row tiles (ty>>...) — keep EXACT r7 shape: 16 ty groups x 4 rows x 2 passes
        // (rewritten below to r7's acc[4][8])
        (void)acc;
      }
      // exact round-7 sim body:
#pragma unroll
      for (int pass = 0; pass < 2; ++pass) {
        const int rc0 = pass * 128 + (tid >> 5) * 4;
        float a4[4];
#pragma unroll
        for (int i = 0; i < 4; ++i) a4[i] = aS[rc0 + i];
        float acc[4][8];
#pragma unroll
        for (int j = 0; j < 8; ++j) {
          const float pj = Ps[tx + 32 * j], qj = Qs[tx + 32 * j];
#pragma unroll
          for (int i = 0; i < 4; ++i) acc[i][j] = a4[i] * pj + qj;
        }
#pragma unroll 8
        for (int k = 0; k < 32; ++k) {
          f32x4 av = *(const f32x4*)&ck0T[k * 260 + rc0];
          float bv[8];
#pragma unroll
          for (int j = 0; j < 8; ++j) bv[j] = dknT[k * 260 + tx + 32 * j];
#pragma unroll
          for (int i = 0; i < 4; ++i)
#pragma unroll
            for (int j = 0; j < 8; ++j) acc[i][j] += av[i] * bv[j];
        }
#pragma unroll
        for (int i = 0; i < 4; ++i) {
          float bvv = -3.0e38f;
          int bi = 1 << 30;
#pragma unroll
          for (int j = 0; j < 8; ++j) {
            int s2 = tx + 32 * j;
            float v = acc[i][j];
            if (s2 == 0) v = -1.0e30f;  // SINK
            if (v > bvv || (v == bvv && s2 < bi)) { bvv = v; bi = s2; }
          }
#pragma unroll
          for (int o = 16; o; o >>= 1) {
            float ov = __shfl_xor(bvv, o);
            int oi = __shfl_xor(bi, o);
            if (ov > bvv || (ov == bvv && oi < bi)) { bvv = ov; bi = oi; }
          }
          if (tx == 0) best[rc0 + i] = bi;
        }
      }
      __syncthreads();
    }

    // ---- phase D: ownership scatter into registers (int4 scan)
    {
      int cadd = 0;
      for (int rc4 = 0; rc4 < 64; ++rc4) {
        const int4 b4 = *(const int4*)&best[rc4 * 4];
#pragma unroll
        for (int u = 0; u < 4; ++u) {
          const int bm = (u == 0) ? b4.x : (u == 1) ? b4.y : (u == 2) ? b4.z : b4.w;
          if (bm == s) {
            const int rc = rc4 * 4 + u;
            const float kwv = kwS[rc];
            if (qd < 2) {
              const float a = aS[rc];
#pragma unroll
              for (int i = 0; i < 16; ++i)
                dkReg[i] += (a * lwS[db + i] + lbS[db + i]) * kwv;
            } else {
#pragma unroll
              for (int i = 0; i < 16; ++i)
                dkReg[i] += ck0T[(db - 32 + i) * 260 + rc] * kwv;
            }
            const uint4 u0 = *(const uint4*)&VRow[rc * 72 + db];
            const uint4 u1 = *(const uint4*)&VRow[rc * 72 + db + 8];
            const unsigned uu[8] = {u0.x, u0.y, u0.z, u0.w, u1.x, u1.y, u1.z, u1.w};
#pragma unroll
            for (int i2 = 0; i2 < 8; ++i2) {
              dvReg[2 * i2] += __uint_as_float((uu[i2] & 0xFFFFu) << 16) * kwv;
              dvReg[2 * i2 + 1] += __uint_as_float(uu[i2] & 0xFFFF0000u) * kwv;
            }
            ++cadd;
          }
        }
      }
      cnt += (float)cadd;
    }
    __syncthreads();
  }
}

// Phase B: MFMA flash attention. Grid 1024 = (bh, c, half); 256 thr, 4 waves x 32 rows.
__global__ __launch_bounds__(256, 2) void attn_mfma_kernel(
    const unsigned short* __restrict__ q_bf, const unsigned short* __restrict__ k_bf,
    const unsigned short* __restrict__ v_bf,
    const unsigned short* __restrict__ dkn_bf, const unsigned short* __restrict__ vst_bf,
    const float* __restrict__ cnt_snap, float* __restrict__ y,
    const float* __restrict__ ftp, const float* __restrict__ stp)
{
  const int blk = blockIdx.x;
  const int bh = blk >> 4;
  const int c = (blk >> 1) & 7;
  const int half = blk & 1;
  const int h = bh & (Hq - 1);
  const int tid = threadIdx.x;
  const int w = tid >> 6, l = tid & 63;
  const int g = l >> 4, n = l & 15;
  const int rows0 = c * 256 + half * 128 + w * 32;
  const int e = c * 256 + 256;
  const int bb = (e - 512 > 0) ? (e - 512) : 0;
  const int nwt = (e - bb) >> 6;  // 4 or 8
  const float stsc = stp[h] * 0.125f, ftsc = ftp[h] * 0.125f;
  const size_t seq = (size_t)Tq * Nq;

  __shared__ unsigned short Ks[64 * 72];
  __shared__ unsigned short VTs[64 * 72];
  __shared__ unsigned short Ps[4][32 * 72];
  __shared__ float wts[64];

  short8v qf[2][2];
#pragma unroll
  for (int mt = 0; mt < 2; ++mt)
#pragma unroll
    for (int kh = 0; kh < 2; ++kh)
      qf[mt][kh] = *(const short8v*)(q_bf + (size_t)bh * seq +
                                     (size_t)(rows0 + mt * 16 + n) * 64 + kh * 32 + g * 8);

  f32x4 oacc[2][4];
#pragma unroll
  for (int mt = 0; mt < 2; ++mt)
#pragma unroll
    for (int dt = 0; dt < 4; ++dt) oacc[mt][dt] = (f32x4){0.f, 0.f, 0.f, 0.f};
  float rowM[2][4], rowL[2][4];
#pragma unroll
  for (int mt = 0; mt < 2; ++mt)
#pragma unroll
    for (int r = 0; r < 4; ++r) { rowM[mt][r] = -1.0e30f; rowL[mt][r] = 0.f; }

  const int nkt = 4 + nwt;
  for (int kt = 0; kt < nkt; ++kt) {
    const bool isState = kt < 4;
    const int t0 = isState ? kt * 64 : bb + (kt - 4) * 64;
    const unsigned short* ksrc = isState
        ? dkn_bf + (((size_t)bh * 8 + c) << 14) + (size_t)t0 * 64
        : k_bf + (size_t)bh * seq + (size_t)t0 * 64;
    const unsigned short* vsrc = isState
        ? vst_bf + (((size_t)bh * 8 + c) << 14) + (size_t)t0 * 64
        : v_bf + (size_t)bh * seq + (size_t)t0 * 64;

    __syncthreads();
    {
      const int row = tid >> 2, q4 = tid & 3;
      const unsigned short* src = ksrc + row * 64 + q4 * 16;
      *(uint4*)&Ks[row * 72 + q4 * 16] = *(const uint4*)src;
      *(uint4*)&Ks[row * 72 + q4 * 16 + 8] = *(const uint4*)(src + 8);
      const unsigned short* vs = vsrc + row * 64 + q4 * 16;
#pragma unroll
      for (int i = 0; i < 16; ++i) VTs[(q4 * 16 + i) * 72 + row] = vs[i];
      if (tid < 64)
        wts[tid] = isState ? cnt_snap[((size_t)bh * 8 + c) * 256 + kt * 64 + tid] : 1.0f;
    }
    __syncthreads();

    f32x4 sacc[2][4];
#pragma unroll
    for (int mt = 0; mt < 2; ++mt)
#pragma unroll
      for (int nt = 0; nt < 4; ++nt) sacc[mt][nt] = (f32x4){0.f, 0.f, 0.f, 0.f};
#pragma unroll
    for (int nt = 0; nt < 4; ++nt) {
      short8v kf0 = *(const short8v*)&Ks[(nt * 16 + n) * 72 + g * 8];
      short8v kf1 = *(const short8v*)&Ks[(nt * 16 + n) * 72 + 32 + g * 8];
#pragma unroll
      for (int mt = 0; mt < 2; ++mt) {
        sacc[mt][nt] = __builtin_amdgcn_mfma_f32_16x16x32_bf16(qf[mt][0], kf0, sacc[mt][nt], 0, 0, 0);
        sacc[mt][nt] = __builtin_amdgcn_mfma_f32_16x16x32_bf16(qf[mt][1], kf1, sacc[mt][nt], 0, 0, 0);
      }
    }

    const float scale = isState ? stsc : ftsc;
    float wt_n[4];
#pragma unroll
    for (int nt = 0; nt < 4; ++nt) wt_n[nt] = wts[nt * 16 + n];

#pragma unroll
    for (int mt = 0; mt < 2; ++mt) {
#pragma unroll
      for (int r = 0; r < 4; ++r) {
        float sv[4];
#pragma unroll
        for (int nt = 0; nt < 4; ++nt) {
          float s = sacc[mt][nt][r] * scale;
          if (!isState) {
            int qi = rows0 + mt * 16 + g * 4 + r;
            int kj = t0 + nt * 16 + n;
            if (kj > qi) s = -1.0e30f;
          }
          sv[nt] = s;
        }
        float tmax = fmaxf(fmaxf(sv[0], sv[1]), fmaxf(sv[2], sv[3]));
        tmax = fmaxf(tmax, __shfl_xor(tmax, 1));
        tmax = fmaxf(tmax, __shfl_xor(tmax, 2));
        tmax = fmaxf(tmax, __shfl_xor(tmax, 4));
        tmax = fmaxf(tmax, __shfl_xor(tmax, 8));
        const float Mold = rowM[mt][r];
        const float Mnew = fmaxf(Mold, tmax);
        const float al = __expf(Mold - Mnew);
        rowM[mt][r] = Mnew;
        float p[4], ts = 0.f;
#pragma unroll
        for (int nt = 0; nt < 4; ++nt) { p[nt] = __expf(sv[nt] - Mnew); ts += p[nt]; }
        ts += __shfl_xor(ts, 1);
        ts += __shfl_xor(ts, 2);
        ts += __shfl_xor(ts, 4);
        ts += __shfl_xor(ts, 8);
        rowL[mt][r] = rowL[mt][r] * al + ts;
#pragma unroll
        for (int dt = 0; dt < 4; ++dt) oacc[mt][dt][r] *= al;
        const int prow = (mt * 16 + g * 4 + r) * 72;
#pragma unroll
        for (int nt = 0; nt < 4; ++nt)
          Ps[w][prow + nt * 16 + n] = f2bf(p[nt] * wt_n[nt]);
      }
    }

    short8v pf[2][2];
#pragma unroll
    for (int mt = 0; mt < 2; ++mt)
#pragma unroll
      for (int jh = 0; jh < 2; ++jh)
        pf[mt][jh] = *(const short8v*)&Ps[w][(mt * 16 + n) * 72 + jh * 32 + g * 8];
#pragma unroll
    for (int dt = 0; dt < 4; ++dt) {
      short8v vf0 = *(const short8v*)&VTs[(dt * 16 + n) * 72 + g * 8];
      short8v vf1 = *(const short8v*)&VTs[(dt * 16 + n) * 72 + 32 + g * 8];
#pragma unroll
      for (int mt = 0; mt < 2; ++mt) {
        oacc[mt][dt] = __builtin_amdgcn_mfma_f32_16x16x32_bf16(pf[mt][0], vf0, oacc[mt][dt], 0, 0, 0);
        oacc[mt][dt] = __builtin_amdgcn_mfma_f32_16x16x32_bf16(pf[mt][1], vf1, oacc[mt][dt], 0, 0, 0);
      }
    }
  }

#pragma unroll
  for (int mt = 0; mt < 2; ++mt) {
#pragma unroll
    for (int r = 0; r < 4; ++r) {
      const float inv = 1.0f / rowL[mt][r];
      const int row = rows0 + mt * 16 + g * 4 + r;
#pragma unroll
      for (int dt = 0; dt < 4; ++dt)
        y[(size_t)bh * seq + (size_t)row * 64 + dt * 16 + n] = oacc[mt][dt][r] * inv;
    }
  }
}

// LN over C=1024 per (b,t); gathers from (B,H,T,N), writes bf16 (B,T,C)
__global__ __launch_bounds__(256) void final_ln(
    const float* __restrict__ y, const float* __restrict__ lnw,
    const float* __restrict__ lnb, unsigned short* __restrict__ dst)
{
  const int bt = blockIdx.x;
  const int b = bt >> 11, t = bt & (Tq - 1);
  const int tid = threadIdx.x, w = tid >> 6, lane = tid & 63;
  __shared__ float red[8];
  float v[4];
  float s = 0.0f;
#pragma unroll
  for (int i = 0; i < 4; ++i) {
    int c = tid + (i << 8);
    int h = c >> 6, n = c & 63;
    v[i] = y[((((size_t)b * Hq + h) * Tq + t) << 6) + n];
    s += v[i];
  }
  s = waveSum(s);
  if (lane == 0) red[w] = s;
  __syncthreads();
  const float mean = (red[0] + red[1] + red[2] + red[3]) * (1.0f / 1024.0f);
  float s2 = 0.0f;
#pragma unroll
  for (int i = 0; i < 4; ++i) { float d = v[i] - mean; s2 += d * d; }
  s2 = waveSum(s2);
  if (lane == 0) red[4 + w] = s2;
  __syncthreads();
  const float var = (red[4] + red[5] + red[6] + red[7]) * (1.0f / 1024.0f);
  const float rs = rsqrtf(var + 1e-5f);
#pragma unroll
  for (int i = 0; i < 4; ++i) {
    int c = tid + (i << 8);
    dst[(size_t)bt * Cq + c] = f2bf((v[i] - mean) * rs * lnw[c] + lnb[c]);
  }
}

extern "C" void kernel_launch(void* const* d_in, const int* in_sizes, int n_in,
                              void* d_out, int out_size, void* d_ws, size_t ws_size,
                              hipStream_t stream)
{
  (void)in_sizes; (void)n_in; (void)out_size; (void)ws_size;
  const float* residual = (const float*)d_in[0];
  const float* x        = (const float*)d_in[1];
  const float* v1       = (const float*)d_in[2];
  const float* Wq       = (const float*)d_in[6];
  const float* Wk       = (const float*)d_in[7];
  const float* Wv       = (const float*)d_in[8];
  const float* Wproj    = (const float*)d_in[9];
  const float* Wkw      = (const float*)d_in[10];
  const float* x_q      = (const float*)d_in[11];
  const float* x_k      = (const float*)d_in[12];
  const float* x_v      = (const float*)d_in[13];
  const float* lamb     = (const float*)d_in[14];
  const float* ln_q_w   = (const float*)d_in[15];
  const float* ln_q_b   = (const float*)d_in[16];
  const float* ln_k_w   = (const float*)d_in[17];
  const float* ln_k_b   = (const float*)d_in[18];
  const float* ln_dk_w  = (const float*)d_in[19];
  const float* ln_dk_b  = (const float*)d_in[20];
  const float* ln_res_w = (const float*)d_in[21];
  const float* ln_res_b = (const float*)d_in[22];
  const float* ftp      = (const float*)d_in[23];
  const float* stp      = (const float*)d_in[24];

  float* ws = (float*)d_ws;
  const size_t SZ = (size_t)Bq * Hq * Tq * Nq;  // 8388608
  float* q_raw = ws;
  float* ybuf  = ws;
  float* k_raw = ws + SZ;
  unsigned short* vst_bf = (unsigned short*)(ws + SZ);
  float* cnt_snap = ws + SZ + SZ / 2;
  float* v_mix = ws + 2 * SZ;
  unsigned short* ylnb_bf = (unsigned short*)(ws + 2 * SZ);
  float* k_fin = ws + 3 * SZ;
  unsigned short* q_bf = (unsigned short*)(ws + 4 * SZ);
  unsigned short* x_lo = q_bf;
  unsigned short* k_bf = q_bf + SZ;
  unsigned short* wk_hi = k_bf;
  unsigned short* wk_lo = wk_hi + (1u << 20);
  unsigned short* v_bf = (unsigned short*)(ws + 5 * SZ);
  unsigned short* xb   = v_bf + SZ;
  unsigned short* dkn_bf = xb;
  unsigned short* wqb = (unsigned short*)(ws + 6 * SZ);
  unsigned short* wvb = wqb + (1u << 20);
  unsigned short* wpb = wvb + (1u << 20);
  float* kwbuf = ws + 6 * SZ + ((3u << 20) >> 1);

  dim3 gb(256);
  dim3 ggb(64, 8);

  hipLaunchKernelGGL(f32_to_bf16_hilo_kernel, dim3((int)(SZ / 4 / 256)), gb, 0, stream,
                     x, xb, x_lo, (int)(SZ / 4));
  hipLaunchKernelGGL(f32_to_bf16_hilo_kernel, dim3(1024), gb, 0, stream,
                     Wk, wk_hi, wk_lo, 262144);
  hipLaunchKernelGGL(f32_to_bf16_kernel, dim3(1024), gb, 0, stream, Wq, wqb, 262144);
  hipLaunchKernelGGL(f32_to_bf16_kernel, dim3(1024), gb, 0, stream, Wv, wvb, 262144);
  hipLaunchKernelGGL(f32_to_bf16_kernel, dim3(1024), gb, 0, stream, Wproj, wpb, 262144);

  hipLaunchKernelGGL(gemm_bf16, ggb, gb, 0, stream, xb, wqb, q_raw, (const float*)nullptr, lamb, 1);
  hipLaunchKernelGGL(gemm_bf16_split, ggb, gb, 0, stream, xb, x_lo, wk_hi, wk_lo, k_raw);
  hipLaunchKernelGGL(gemm_bf16, ggb, gb, 0, stream, xb, wvb, v_mix, v1, lamb, 2);
  hipLaunchKernelGGL(kw_kernel, dim3(Bq * Tq), gb, 0, stream, x, Wkw, kwbuf);

  const int rows = Bq * Hq * Tq;
  hipLaunchKernelGGL(postproc, dim3(rows / 4), gb, 0, stream, q_raw, (float*)nullptr, q_bf, ln_q_w, ln_q_b, x_q, 1);
  hipLaunchKernelGGL(postproc, dim3(rows / 4), gb, 0, stream, k_raw, k_fin, k_bf, ln_k_w, ln_k_b, x_k, 1);
  hipLaunchKernelGGL(postproc, dim3(rows / 4), gb, 0, stream, v_mix, (float*)nullptr, v_bf,
                     (const float*)nullptr, (const float*)nullptr, x_v, 0);

  hipLaunchKernelGGL(state_evolve_kernel, dim3(Bq * Hq), dim3(1024), 0, stream,
                     k_fin, v_bf, kwbuf, dkn_bf, vst_bf, cnt_snap, ln_dk_w, ln_dk_b);

  hipLaunchKernelGGL(attn_mfma_kernel, dim3(Bq * Hq * 16), gb, 0, stream,
                     q_bf, k_bf, v_bf, dkn_bf, vst_bf, cnt_snap, ybuf, ftp, stp);

  hipLaunchKernelGGL(final_ln, dim3(Bq * Tq), gb, 0, stream, ybuf, ln_res_w, ln_res_b, ylnb_bf);
  hipLaunchKernelGGL(gemm_bf16, ggb, gb, 0, stream, ylnb_bf, wpb, (float*)d_out, residual, lamb, 3);
}